// Round 4
// baseline (293.206 us; speedup 1.0000x reference)
//
#include <hip/hip_runtime.h>
#include <hip/hip_bf16.h>

typedef unsigned short ushort_t;
typedef short short8_t __attribute__((ext_vector_type(8)));
typedef float f32x4 __attribute__((ext_vector_type(4)));
typedef float f32x16 __attribute__((ext_vector_type(16)));
typedef ushort_t us4_t __attribute__((ext_vector_type(4)));

#define NBATCH 16
#define SEQ    60
#define NSTK   50
#define HID    128
#define G3     384
#define NIMG   800
#define IH     64
#define IW     60
#define P1H    32
#define P1W    30
#define P2C    64
#define FCIN   15360

// ---- workspace layout (float offsets) ----
#define OFF_WHHF   0u          // 49152 ushort  = 24576 f
#define OFF_WPREP  24576u      // 18432 ushort  = 9216 f
#define OFF_WFC1   33792u      // 983040 ushort = 491520 f
#define OFF_GI     525312u     // 368640 f
#define OFF_HLAST  893952u     // 2048 f
#define OFF_POOL2  896000u     // 800*15360 bf16 = 6144000 f
#define OFF_FC2O   7040000u    // 102400 f
#define WS_FLOATS  7142400u    // ~28.6 MB

// swizzle element counts for k_pre
#define E_WHH  49152
#define E_WPR  18432
#define E_FC1  983040
#define E_TOT  (E_WHH + E_WPR + E_FC1)   // 1050624 = 2736*384

// ---------------- shared-memory layouts for the mega kernel ----------------
struct __align__(16) ConvS {
    ushort_t pool1t[32][4][32][8];     // 65536 B  [y][cg][xs][ch8], xs=x+1; xs 0,31 zeroed
    float    imgp[64][60];             // 15360 B  unpadded image
};                                      // 80896 B  -> 2 blocks/CU
struct __align__(16) GruS {
    float    gh[16 * 388];             // 24832 B
    ushort_t hb[16 * 136];             //  4352 B
};                                      // 29184 B
#define SMEM_BYTES 80896

__device__ __forceinline__ float fast_sig(float x) {
    const float e = __expf(-x);
    return __builtin_amdgcn_rcpf(1.f + e);
}
__device__ __forceinline__ float fast_tanh(float x) {
    const float xc = fmaxf(fminf(x, 15.f), -15.f);
    const float e = __expf(2.f * xc);
    return (e - 1.f) * __builtin_amdgcn_rcpf(e + 1.f);
}

// ---------------- k_pre: GI (blocks 0..959) + weight swizzles (960..) ----------------
__global__ __launch_bounds__(384) void k_pre(const float* __restrict__ xnum,
                                             const float* __restrict__ wih,
                                             const float* __restrict__ bih,
                                             const float* __restrict__ whh,
                                             const float* __restrict__ c2w,
                                             const float* __restrict__ fc1w,
                                             float* __restrict__ GI,
                                             ushort_t* __restrict__ whhf,
                                             ushort_t* __restrict__ wprep,
                                             ushort_t* __restrict__ wfc1)
{
    const int bid = blockIdx.x;
    if (bid < 960) {
        const int s = bid >> 4, b = bid & 15;
        const int j = threadIdx.x;
        const float* xr = xnum + (size_t)(b * SEQ + s) * NSTK;   // wave-uniform -> scalar loads
        const float* wr = wih + (size_t)j * NSTK;
        float a = bih[j];
        #pragma unroll 10
        for (int k = 0; k < NSTK; ++k) a = fmaf(xr[k], wr[k], a);
        GI[((size_t)s * 16 + b) * G3 + j] = a;
        return;
    }
    const int idx = (bid - 960) * 384 + threadIdx.x;
    if (idx < E_WHH) {
        const int e = idx;                  // (((jt*4+ks)*64 + l)*8 + i)
        const int i = e & 7, l = (e >> 3) & 63, ksj = e >> 9;
        const int ks = ksj & 3, jt = ksj >> 2;
        const int j = jt * 16 + (l & 15);
        const int k = ks * 32 + ((l >> 4) << 3) + i;
        __hip_bfloat16 hv = __float2bfloat16(whh[j * HID + k]);
        whhf[e] = *(ushort_t*)&hv;
    } else if (idx < E_WHH + E_WPR) {
        const int e = idx - E_WHH;          // (((m*9+tap)*2+ks)*64 + l)*8 + i
        const int i = e & 7, l = (e >> 3) & 63, rest = e >> 9;
        const int ks = rest & 1, mt = rest >> 1;
        const int tap = mt % 9, mm = mt / 9;
        const int oc = mm * 32 + (l & 31);
        const int ic = ks * 16 + ((l >> 5) << 3) + i;
        __hip_bfloat16 hv = __float2bfloat16(c2w[((size_t)oc * 32 + ic) * 9 + tap]);
        wprep[e] = *(ushort_t*)&hv;
    } else if (idx < E_TOT) {
        const int e = idx - (E_WHH + E_WPR); // ((T*4+n)*64 + l)*8 + i
        const int i = e & 7, l = (e >> 3) & 63, rest = e >> 9;
        const int n = rest & 3, T = rest >> 2;
        const int oc = n * 16 + (l & 15);
        const int k = T * 32 + ((l >> 4) << 3) + i;
        __hip_bfloat16 hv = __float2bfloat16(fc1w[(size_t)oc * FCIN + k]);
        wfc1[e] = *(ushort_t*)&hv;
    }
}

// ---------------- mega kernel: block 0 = GRU, blocks 1..800 = one image each ----
__global__ __launch_bounds__(512, 4) void k_mega(const float* __restrict__ x_img,
                                                 const float* __restrict__ c1w,
                                                 const float* __restrict__ c1b,
                                                 const float* __restrict__ c2b,
                                                 const ushort_t* __restrict__ wprep,
                                                 const float* __restrict__ GI,
                                                 const ushort_t* __restrict__ whhf,
                                                 const float* __restrict__ bhh,
                                                 ushort_t* __restrict__ pool2,
                                                 float* __restrict__ hlast)
{
    extern __shared__ char smraw[];
    const int tid = threadIdx.x;
    const int bid = blockIdx.x;

    if (bid == 0) {
        // =========== GRU: W_hh frags in regs, GI prefetch, h in regs ===========
        GruS* g = (GruS*)smraw;
        const int w = tid >> 6, l = tid & 63;
        const int arow = l & 15, kq = l >> 4;
        short8_t wfr[3][4];
        #pragma unroll
        for (int jj = 0; jj < 3; ++jj)
            #pragma unroll
            for (int ks = 0; ks < 4; ++ks)
                wfr[jj][ks] = *(const short8_t*)&whhf[((((w * 3 + jj) * 4 + ks) * 64 + l) * 8)];

        const int b = tid >> 5, hh0 = (tid & 31) * 4;
        const f32x4 bhr = *(const f32x4*)&bhh[hh0];
        const f32x4 bhz = *(const f32x4*)&bhh[128 + hh0];
        const f32x4 bhn = *(const f32x4*)&bhh[256 + hh0];
        float h0 = 0.f, h1 = 0.f, h2 = 0.f, h3 = 0.f;
        for (int i = tid; i < 1088; i += 512) ((unsigned int*)g->hb)[i] = 0u;
        const float* gi0 = GI + b * G3 + hh0;
        f32x4 cr = *(const f32x4*)(gi0);
        f32x4 cz = *(const f32x4*)(gi0 + 128);
        f32x4 cn = *(const f32x4*)(gi0 + 256);
        __syncthreads();

        for (int s = 0; s < SEQ; ++s) {
            const int sn = (s + 1 < SEQ) ? s + 1 : s;
            const float* gnx = GI + ((size_t)sn * 16 + b) * G3 + hh0;
            const f32x4 nr = *(const f32x4*)(gnx);
            const f32x4 nz = *(const f32x4*)(gnx + 128);
            const f32x4 nn = *(const f32x4*)(gnx + 256);

            #pragma unroll
            for (int jj = 0; jj < 3; ++jj) {
                f32x4 a = {0.f, 0.f, 0.f, 0.f};
                #pragma unroll
                for (int ks = 0; ks < 4; ++ks) {
                    short8_t af = *(const short8_t*)&g->hb[arow * 136 + ks * 32 + kq * 8];
                    a = __builtin_amdgcn_mfma_f32_16x16x32_bf16(af, wfr[jj][ks], a, 0, 0, 0);
                }
                const int jt = w * 3 + jj;
                #pragma unroll
                for (int r = 0; r < 4; ++r)
                    g->gh[(kq * 4 + r) * 388 + jt * 16 + arow] = a[r];
            }
            __syncthreads();

            const f32x4 gr = *(const f32x4*)&g->gh[b * 388 + hh0];
            const f32x4 gz = *(const f32x4*)&g->gh[b * 388 + 128 + hh0];
            const f32x4 gn = *(const f32x4*)&g->gh[b * 388 + 256 + hh0];
            float hv0, hv1, hv2, hv3;
            {
                const float r0 = fast_sig(cr[0] + gr[0] + bhr[0]);
                const float z0 = fast_sig(cz[0] + gz[0] + bhz[0]);
                const float n0 = fast_tanh(cn[0] + r0 * (gn[0] + bhn[0]));
                hv0 = (1.f - z0) * n0 + z0 * h0;
                const float r1 = fast_sig(cr[1] + gr[1] + bhr[1]);
                const float z1 = fast_sig(cz[1] + gz[1] + bhz[1]);
                const float n1 = fast_tanh(cn[1] + r1 * (gn[1] + bhn[1]));
                hv1 = (1.f - z1) * n1 + z1 * h1;
                const float r2 = fast_sig(cr[2] + gr[2] + bhr[2]);
                const float z2 = fast_sig(cz[2] + gz[2] + bhz[2]);
                const float n2 = fast_tanh(cn[2] + r2 * (gn[2] + bhn[2]));
                hv2 = (1.f - z2) * n2 + z2 * h2;
                const float r3 = fast_sig(cr[3] + gr[3] + bhr[3]);
                const float z3 = fast_sig(cz[3] + gz[3] + bhz[3]);
                const float n3 = fast_tanh(cn[3] + r3 * (gn[3] + bhn[3]));
                hv3 = (1.f - z3) * n3 + z3 * h3;
            }
            h0 = hv0; h1 = hv1; h2 = hv2; h3 = hv3;
            us4_t hp;
            { __hip_bfloat16 t0 = __float2bfloat16(h0); hp[0] = *(ushort_t*)&t0; }
            { __hip_bfloat16 t1 = __float2bfloat16(h1); hp[1] = *(ushort_t*)&t1; }
            { __hip_bfloat16 t2 = __float2bfloat16(h2); hp[2] = *(ushort_t*)&t2; }
            { __hip_bfloat16 t3 = __float2bfloat16(h3); hp[3] = *(ushort_t*)&t3; }
            *(us4_t*)&g->hb[b * 136 + hh0] = hp;
            cr = nr; cz = nz; cn = nn;
            __syncthreads();
        }
        f32x4 ho = {h0, h1, h2, h3};
        *(f32x4*)&hlast[b * HID + hh0] = ho;
        return;
    }

    // ======================= CNN branch, one image per block =======================
    ConvS* c = (ConvS*)smraw;
    const int img = bid - 1;
    const float* xim = x_img + (size_t)img * (IH * IW);

    // zero the xs=0 / xs=31 halo columns of pool1t
    if (tid < 256) {
        const int y = tid >> 3, cg = (tid >> 1) & 3, xs = (tid & 1) * 31;
        short8_t z = {0, 0, 0, 0, 0, 0, 0, 0};
        *(short8_t*)&c->pool1t[y][cg][xs][0] = z;
    }
    // copy image to LDS (float4)
    {
        const f32x4* src = (const f32x4*)xim;
        f32x4* dst = (f32x4*)c->imgp;
        for (int i = tid; i < 3840; i += 512) dst[i] = src[i];
    }
    __syncthreads();

    // ---- conv1+relu+pool1: thread = pooled position; channel loop, uniform weights ----
    #pragma unroll
    for (int rep = 0; rep < 2; ++rep) {
        const int p = tid + rep * 512;
        if (p < 960) {
            const int py = p / 30, px = p - py * 30;
            float patch[4][4];
            #pragma unroll
            for (int yy = 0; yy < 4; ++yy) {
                const int iy = 2 * py - 1 + yy;
                #pragma unroll
                for (int xx = 0; xx < 4; ++xx) {
                    const int ix = 2 * px - 1 + xx;
                    patch[yy][xx] = (iy >= 0 && iy < IH && ix >= 0 && ix < IW)
                                        ? c->imgp[iy][ix] : 0.f;
                }
            }
            #pragma unroll
            for (int cg = 0; cg < 4; ++cg) {
                short8_t outv;
                #pragma unroll
                for (int ch8 = 0; ch8 < 8; ++ch8) {
                    const int ch = cg * 8 + ch8;
                    float wr[9];
                    #pragma unroll
                    for (int q = 0; q < 9; ++q) wr[q] = c1w[ch * 9 + q];   // wave-uniform -> SGPR
                    const float bia = c1b[ch];
                    float best = 0.f;
                    #pragma unroll
                    for (int dy = 0; dy < 2; ++dy)
                        #pragma unroll
                        for (int dx = 0; dx < 2; ++dx) {
                            float sv = 0.f;
                            #pragma unroll
                            for (int ky = 0; ky < 3; ++ky)
                                #pragma unroll
                                for (int kx = 0; kx < 3; ++kx)
                                    sv = fmaf(patch[dy + ky][dx + kx], wr[ky * 3 + kx], sv);
                            best = fmaxf(best, sv + bia);
                        }
                    __hip_bfloat16 hv = __float2bfloat16(best);
                    outv[ch8] = *(short*)&hv;
                }
                *(short8_t*)&c->pool1t[py][cg][px + 1][0] = outv;
            }
        }
    }
    __syncthreads();

    // ---- conv2 via bf16 MFMA 32x32x16 implicit GEMM + fused relu/pool2, direct stores ----
    {
        const int w  = tid >> 6, l = tid & 63;
        const int m  = w & 1;
        const int hi = l >> 5;
        const int col = l & 31;

        short8_t af[9][2];
        #pragma unroll
        for (int tap = 0; tap < 9; ++tap)
            #pragma unroll
            for (int ks = 0; ks < 2; ++ks)
                af[tap][ks] = *(const short8_t*)&wprep[(((m * 9 + tap) * 2 + ks) * 64 + l) * 8];
        float bia[16];
        #pragma unroll
        for (int r = 0; r < 16; ++r)
            bia[r] = c2b[m * 32 + (r & 3) + 8 * (r >> 2) + 4 * hi];

        const bool wr = ((col & 1) == 0) && (col < 30);
        const int px = col >> 1;
        ushort_t* p2b = pool2 + (size_t)img * FCIN + px;
        const short8_t bfz = {0, 0, 0, 0, 0, 0, 0, 0};

        for (int yp = (w >> 1); yp < 16; yp += 4) {
            f32x16 a0, a1;
            #pragma unroll
            for (int r = 0; r < 16; ++r) { a0[r] = 0.f; a1[r] = 0.f; }
            #pragma unroll
            for (int ro = 0; ro < 4; ++ro) {
                const int y = 2 * yp - 1 + ro;
                short8_t bf[3][2];
                if (y >= 0 && y < 32) {     // wave-uniform
                    #pragma unroll
                    for (int kx = 0; kx < 3; ++kx)
                        #pragma unroll
                        for (int ks = 0; ks < 2; ++ks)
                            bf[kx][ks] = *(const short8_t*)&c->pool1t[y][ks * 2 + hi][kx + col][0];
                } else {
                    #pragma unroll
                    for (int kx = 0; kx < 3; ++kx)
                        #pragma unroll
                        for (int ks = 0; ks < 2; ++ks) bf[kx][ks] = bfz;
                }
                if (ro < 3) {
                    #pragma unroll
                    for (int kx = 0; kx < 3; ++kx)
                        #pragma unroll
                        for (int ks = 0; ks < 2; ++ks)
                            a0 = __builtin_amdgcn_mfma_f32_32x32x16_bf16(af[ro * 3 + kx][ks], bf[kx][ks], a0, 0, 0, 0);
                }
                if (ro >= 1) {
                    #pragma unroll
                    for (int kx = 0; kx < 3; ++kx)
                        #pragma unroll
                        for (int ks = 0; ks < 2; ++ks)
                            a1 = __builtin_amdgcn_mfma_f32_32x32x16_bf16(af[(ro - 1) * 3 + kx][ks], bf[kx][ks], a1, 0, 0, 0);
                }
            }
            #pragma unroll
            for (int r = 0; r < 16; ++r) {
                float v = fmaxf(a0[r], a1[r]);
                v = fmaxf(v, __shfl_xor(v, 1, 64));
                v = fmaxf(v + bia[r], 0.f);
                if (wr) {
                    const int oc = m * 32 + (r & 3) + 8 * (r >> 2) + 4 * hi;
                    __hip_bfloat16 hv = __float2bfloat16(v);
                    p2b[oc * 240 + yp * 15] = *(ushort_t*)&hv;
                }
            }
        }
    }
}

// -------- fc1 (full-K MFMA) + relu + binary head + fc2, 16 images/block --------
__global__ __launch_bounds__(256) void k_fc1post(const ushort_t* __restrict__ pool2,
                                                 const ushort_t* __restrict__ wfc1,
                                                 const float* __restrict__ fc1b,
                                                 const float* __restrict__ fbw,
                                                 const float* __restrict__ fbb,
                                                 const float* __restrict__ fc2w,
                                                 const float* __restrict__ fc2b,
                                                 float* __restrict__ out,
                                                 float* __restrict__ fc2o)
{
    const int mt = blockIdx.x;                  // 0..49
    const int w = threadIdx.x >> 6, l = threadIdx.x & 63;
    const int arow = l & 15, kq = l >> 4;
    const int img16 = mt * 16;
    const ushort_t* Ab = pool2 + (size_t)(img16 + arow) * FCIN + kq * 8;
    const ushort_t* Bb = wfc1 + (size_t)w * 512 + (size_t)l * 8;
    f32x4 acc0 = {0.f, 0.f, 0.f, 0.f}, acc1 = {0.f, 0.f, 0.f, 0.f};
    #pragma unroll 4
    for (int T = 0; T < 480; T += 2) {
        const short8_t aA = *(const short8_t*)(Ab + (size_t)T * 32);
        const short8_t bA = *(const short8_t*)(Bb + (size_t)T * 2048);
        const short8_t aB = *(const short8_t*)(Ab + (size_t)(T + 1) * 32);
        const short8_t bB = *(const short8_t*)(Bb + (size_t)(T + 1) * 2048);
        acc0 = __builtin_amdgcn_mfma_f32_16x16x32_bf16(aA, bA, acc0, 0, 0, 0);
        acc1 = __builtin_amdgcn_mfma_f32_16x16x32_bf16(aB, bB, acc1, 0, 0, 0);
    }
    __shared__ float fl[16][64];
    const int oc = w * 16 + (l & 15);
    #pragma unroll
    for (int r = 0; r < 4; ++r)
        fl[kq * 4 + r][oc] = fmaxf(acc0[r] + acc1[r] + fc1b[oc], 0.f);
    __syncthreads();

    const int t = threadIdx.x;
    const int im = t >> 4;                       // 0..15
    float bs = 0.f;
    #pragma unroll
    for (int q = 0; q < 4; ++q) {
        const int k = (t & 15) * 4 + q;
        bs = fmaf(fl[im][k], fbw[k], bs);
    }
    bs += __shfl_xor(bs, 1, 64); bs += __shfl_xor(bs, 2, 64);
    bs += __shfl_xor(bs, 4, 64); bs += __shfl_xor(bs, 8, 64);
    if ((t & 15) == 0) out[800 + img16 + im] = 1.f / (1.f + expf(-(bs + fbb[0])));

    #pragma unroll
    for (int q = 0; q < 8; ++q) {
        const int j = (t & 15) + q * 16;
        float a2 = fc2b[j];
        #pragma unroll 8
        for (int k = 0; k < 64; ++k) a2 = fmaf(fl[im][k], fc2w[j * 64 + k], a2);
        fc2o[(size_t)(img16 + im) * 128 + j] = a2;
    }
}

__device__ __forceinline__ float wave_sum(float v) {
    #pragma unroll
    for (int o = 32; o > 0; o >>= 1) v += __shfl_xor(v, o, 64);
    return v;
}
__device__ __forceinline__ float wave_max(float v) {
    #pragma unroll
    for (int o = 32; o > 0; o >>= 1) v = fmaxf(v, __shfl_xor(v, o, 64));
    return v;
}

// ---------------- fusion + softmax + 32-iter water-filling rebalance --------
__global__ __launch_bounds__(64) void k_final(const float* __restrict__ hlast,
                                              const float* __restrict__ fc2o,
                                              const float* __restrict__ gw,
                                              const float* __restrict__ gb,
                                              const float* __restrict__ fw,
                                              const float* __restrict__ fb,
                                              const float* __restrict__ finw,
                                              const float* __restrict__ finb,
                                              float* __restrict__ out)
{
    const int b = blockIdx.x, t = threadIdx.x;
    __shared__ float cf[128], nf[64], fu[64];
    #pragma unroll
    for (int jj = 0; jj < 2; ++jj) {
        const int j = t + jj * 64;
        float s = 0.f;
        for (int n = 0; n < NSTK; ++n) s += fc2o[(size_t)(b * NSTK + n) * 128 + j];
        cf[j] = s * (1.0f / 50.0f);
    }
    float s = 0.f;
    if (t < NSTK) {
        s = gb[t];
        for (int k = 0; k < HID; ++k) s = fmaf(hlast[b * HID + k], gw[t * HID + k], s);
    }
    nf[t] = (t < NSTK) ? s : 0.f;
    __syncthreads();
    float f = fb[t];
    for (int k = 0; k < NSTK; ++k) f = fmaf(nf[k], fw[t * 178 + k], f);
    for (int k = 0; k < 128; ++k) f = fmaf(cf[k], fw[t * 178 + 50 + k], f);
    fu[t] = fmaxf(f, 0.f);
    __syncthreads();
    float L = -3.4e38f;
    if (t < NSTK) {
        L = finb[t];
        for (int k = 0; k < 64; ++k) L = fmaf(fu[k], finw[t * 64 + k], L);
    }
    const float m = wave_max(L);
    const float e = (t < NSTK) ? expf(L - m) : 0.f;
    const float se = wave_sum(e);
    const float wv = e / se;
    float old = wv;
    float wc = fminf(fmaxf(wv, 0.f), 0.1f);
    for (int it = 0; it < 32; ++it) {
        const float leftover = wave_sum(old - wc);
        const bool mask = (wc != 0.1f);
        const float ssum = wave_sum(mask ? wc : 0.f);
        const float gift = (mask && ssum > 0.f) ? leftover * wc / ssum : 0.f;
        old = wc + gift;
        wc = fminf(fmaxf(old, 0.f), 0.1f);
    }
    if (t < NSTK) out[b * NSTK + t] = wc;
}

// ---------------------------------------------------------------------------
extern "C" void kernel_launch(void* const* d_in, const int* in_sizes, int n_in,
                              void* d_out, int out_size, void* d_ws, size_t ws_size,
                              hipStream_t stream)
{
    const float* x_num = (const float*)d_in[0];
    const float* x_img = (const float*)d_in[1];
    const float* c1w  = (const float*)d_in[2];
    const float* c1b  = (const float*)d_in[3];
    const float* c2w  = (const float*)d_in[4];
    const float* c2b  = (const float*)d_in[5];
    const float* fc1w = (const float*)d_in[6];
    const float* fc1b = (const float*)d_in[7];
    const float* fbw  = (const float*)d_in[8];
    const float* fbb  = (const float*)d_in[9];
    const float* fc2w = (const float*)d_in[10];
    const float* fc2b = (const float*)d_in[11];
    const float* wih  = (const float*)d_in[12];
    const float* whh  = (const float*)d_in[13];
    const float* bih  = (const float*)d_in[14];
    const float* bhh  = (const float*)d_in[15];
    const float* gw   = (const float*)d_in[16];
    const float* gb   = (const float*)d_in[17];
    const float* fw   = (const float*)d_in[18];
    const float* fb   = (const float*)d_in[19];
    const float* finw = (const float*)d_in[20];
    const float* finb = (const float*)d_in[21];
    float* out = (float*)d_out;
    float* ws  = (float*)d_ws;
    if (ws_size < (size_t)WS_FLOATS * 4) return;

    ushort_t* whhf  = (ushort_t*)(ws + OFF_WHHF);
    ushort_t* wprep = (ushort_t*)(ws + OFF_WPREP);
    ushort_t* wfc1  = (ushort_t*)(ws + OFF_WFC1);
    float* GI       = ws + OFF_GI;
    float* hlast    = ws + OFF_HLAST;
    ushort_t* pool2 = (ushort_t*)(ws + OFF_POOL2);
    float* fc2o     = ws + OFF_FC2O;

    (void)hipFuncSetAttribute(reinterpret_cast<const void*>(k_mega),
                              hipFuncAttributeMaxDynamicSharedMemorySize, SMEM_BYTES);

    k_pre    <<<960 + 2736, 384, 0, stream>>>(x_num, wih, bih, whh, c2w, fc1w,
                                              GI, whhf, wprep, wfc1);
    k_mega   <<<NIMG + 1, 512, SMEM_BYTES, stream>>>(x_img, c1w, c1b, c2b, wprep,
                                                     GI, whhf, bhh, pool2, hlast);
    k_fc1post<<<50, 256, 0, stream>>>(pool2, wfc1, fc1b, fbw, fbb, fc2w, fc2b, out, fc2o);
    k_final  <<<NBATCH, 64, 0, stream>>>(hlast, fc2o, gw, gb, fw, fb, finw, finb, out);
}

// Round 5
// 227.956 us; speedup vs baseline: 1.2862x; 1.2862x over previous
//
#include <hip/hip_runtime.h>
#include <hip/hip_bf16.h>

typedef unsigned short ushort_t;
typedef short short8_t __attribute__((ext_vector_type(8)));
typedef float f32x4 __attribute__((ext_vector_type(4)));
typedef float f32x16 __attribute__((ext_vector_type(16)));
typedef ushort_t us4_t __attribute__((ext_vector_type(4)));

#define NBATCH 16
#define SEQ    60
#define NSTK   50
#define HID    128
#define G3     384
#define NIMG   800
#define IH     64
#define IW     60
#define P1H    32
#define P1W    30
#define P2C    64
#define FCIN   15360

// ---- workspace layout (float offsets) ----
#define OFF_WHHF   0u          // 49152 ushort  = 24576 f
#define OFF_WPREP  24576u      // 18432 ushort  = 9216 f
#define OFF_WFC1   33792u      // 983040 ushort = 491520 f
#define OFF_GI     525312u     // 368640 f
#define OFF_HLAST  893952u     // 2048 f
#define OFF_POOL2  896000u     // 800*15360 bf16 = 6144000 f
#define OFF_FC2O   7040000u    // 102400 f
#define WS_FLOATS  7142400u    // ~28.6 MB

// swizzle element counts for k_pre
#define E_WHH  49152
#define E_WPR  18432
#define E_FC1  983040
#define E_TOT  (E_WHH + E_WPR + E_FC1)   // 1050624 = 2736*384

// ---------------- shared-memory layouts for the mega kernel ----------------
struct __align__(16) ConvS {
    ushort_t pool1t[32][4][32][8];     // 65536 B  [y][cg][xs][ch8], xs=x+1; xs 0,31 zeroed
    union {
        float    imgp[64][60];         // 15360 B  (conv1 phase)
        ushort_t pool2s[64][120];      // 15360 B  (conv2 half-tile staging)
    } u;
};                                      // 80896 B  -> 2 blocks/CU
struct __align__(16) GruS {
    float    gh[16 * 388];             // 24832 B
    ushort_t hb[16 * 136];             //  4352 B
};                                      // 29184 B
#define SMEM_BYTES 80896

__device__ __forceinline__ float fast_sig(float x) {
    const float e = __expf(-x);
    return __builtin_amdgcn_rcpf(1.f + e);
}
__device__ __forceinline__ float fast_tanh(float x) {
    const float xc = fmaxf(fminf(x, 15.f), -15.f);
    const float e = __expf(2.f * xc);
    return (e - 1.f) * __builtin_amdgcn_rcpf(e + 1.f);
}

// ---------------- k_pre: GI (blocks 0..959) + weight swizzles (960..) ----------------
__global__ __launch_bounds__(384) void k_pre(const float* __restrict__ xnum,
                                             const float* __restrict__ wih,
                                             const float* __restrict__ bih,
                                             const float* __restrict__ whh,
                                             const float* __restrict__ c2w,
                                             const float* __restrict__ fc1w,
                                             float* __restrict__ GI,
                                             ushort_t* __restrict__ whhf,
                                             ushort_t* __restrict__ wprep,
                                             ushort_t* __restrict__ wfc1)
{
    const int bid = blockIdx.x;
    if (bid < 960) {
        const int s = bid >> 4, b = bid & 15;
        const int j = threadIdx.x;
        const float* xr = xnum + (size_t)(b * SEQ + s) * NSTK;   // wave-uniform -> scalar loads
        const float* wr = wih + (size_t)j * NSTK;
        float a = bih[j];
        #pragma unroll 10
        for (int k = 0; k < NSTK; ++k) a = fmaf(xr[k], wr[k], a);
        GI[((size_t)s * 16 + b) * G3 + j] = a;
        return;
    }
    const int idx = (bid - 960) * 384 + threadIdx.x;
    if (idx < E_WHH) {
        const int e = idx;                  // (((jt*4+ks)*64 + l)*8 + i)
        const int i = e & 7, l = (e >> 3) & 63, ksj = e >> 9;
        const int ks = ksj & 3, jt = ksj >> 2;
        const int j = jt * 16 + (l & 15);
        const int k = ks * 32 + ((l >> 4) << 3) + i;
        __hip_bfloat16 hv = __float2bfloat16(whh[j * HID + k]);
        whhf[e] = *(ushort_t*)&hv;
    } else if (idx < E_WHH + E_WPR) {
        const int e = idx - E_WHH;          // (((m*9+tap)*2+ks)*64 + l)*8 + i
        const int i = e & 7, l = (e >> 3) & 63, rest = e >> 9;
        const int ks = rest & 1, mt = rest >> 1;
        const int tap = mt % 9, mm = mt / 9;
        const int oc = mm * 32 + (l & 31);
        const int ic = ks * 16 + ((l >> 5) << 3) + i;
        __hip_bfloat16 hv = __float2bfloat16(c2w[((size_t)oc * 32 + ic) * 9 + tap]);
        wprep[e] = *(ushort_t*)&hv;
    } else if (idx < E_TOT) {
        const int e = idx - (E_WHH + E_WPR); // ((T*4+n)*64 + l)*8 + i
        const int i = e & 7, l = (e >> 3) & 63, rest = e >> 9;
        const int n = rest & 3, T = rest >> 2;
        const int oc = n * 16 + (l & 15);
        const int k = T * 32 + ((l >> 4) << 3) + i;
        __hip_bfloat16 hv = __float2bfloat16(fc1w[(size_t)oc * FCIN + k]);
        wfc1[e] = *(ushort_t*)&hv;
    }
}

// ---------------- mega kernel: block 0 = GRU, blocks 1..800 = one image each ----
__global__ __launch_bounds__(512, 2) void k_mega(const float* __restrict__ x_img,
                                                 const float* __restrict__ c1w,
                                                 const float* __restrict__ c1b,
                                                 const float* __restrict__ c2b,
                                                 const ushort_t* __restrict__ wprep,
                                                 const float* __restrict__ GI,
                                                 const ushort_t* __restrict__ whhf,
                                                 const float* __restrict__ bhh,
                                                 ushort_t* __restrict__ pool2,
                                                 float* __restrict__ hlast)
{
    extern __shared__ char smraw[];
    const int tid = threadIdx.x;
    const int bid = blockIdx.x;

    if (bid == 0) {
        // =========== GRU: W_hh frags in regs, GI prefetch, h in regs ===========
        GruS* g = (GruS*)smraw;
        const int w = tid >> 6, l = tid & 63;
        const int arow = l & 15, kq = l >> 4;
        short8_t wfr[3][4];
        #pragma unroll
        for (int jj = 0; jj < 3; ++jj)
            #pragma unroll
            for (int ks = 0; ks < 4; ++ks)
                wfr[jj][ks] = *(const short8_t*)&whhf[((((w * 3 + jj) * 4 + ks) * 64 + l) * 8)];

        const int b = tid >> 5, hh0 = (tid & 31) * 4;
        const f32x4 bhr = *(const f32x4*)&bhh[hh0];
        const f32x4 bhz = *(const f32x4*)&bhh[128 + hh0];
        const f32x4 bhn = *(const f32x4*)&bhh[256 + hh0];
        float h0 = 0.f, h1 = 0.f, h2 = 0.f, h3 = 0.f;
        for (int i = tid; i < 1088; i += 512) ((unsigned int*)g->hb)[i] = 0u;
        const float* gi0 = GI + b * G3 + hh0;
        f32x4 cr = *(const f32x4*)(gi0);
        f32x4 cz = *(const f32x4*)(gi0 + 128);
        f32x4 cn = *(const f32x4*)(gi0 + 256);
        __syncthreads();

        for (int s = 0; s < SEQ; ++s) {
            const int sn = (s + 1 < SEQ) ? s + 1 : s;
            const float* gnx = GI + ((size_t)sn * 16 + b) * G3 + hh0;
            const f32x4 nr = *(const f32x4*)(gnx);
            const f32x4 nz = *(const f32x4*)(gnx + 128);
            const f32x4 nn = *(const f32x4*)(gnx + 256);

            #pragma unroll
            for (int jj = 0; jj < 3; ++jj) {
                f32x4 a = {0.f, 0.f, 0.f, 0.f};
                #pragma unroll
                for (int ks = 0; ks < 4; ++ks) {
                    short8_t af = *(const short8_t*)&g->hb[arow * 136 + ks * 32 + kq * 8];
                    a = __builtin_amdgcn_mfma_f32_16x16x32_bf16(af, wfr[jj][ks], a, 0, 0, 0);
                }
                const int jt = w * 3 + jj;
                #pragma unroll
                for (int r = 0; r < 4; ++r)
                    g->gh[(kq * 4 + r) * 388 + jt * 16 + arow] = a[r];
            }
            __syncthreads();

            const f32x4 gr = *(const f32x4*)&g->gh[b * 388 + hh0];
            const f32x4 gz = *(const f32x4*)&g->gh[b * 388 + 128 + hh0];
            const f32x4 gn = *(const f32x4*)&g->gh[b * 388 + 256 + hh0];
            float hv0, hv1, hv2, hv3;
            {
                const float r0 = fast_sig(cr[0] + gr[0] + bhr[0]);
                const float z0 = fast_sig(cz[0] + gz[0] + bhz[0]);
                const float n0 = fast_tanh(cn[0] + r0 * (gn[0] + bhn[0]));
                hv0 = (1.f - z0) * n0 + z0 * h0;
                const float r1 = fast_sig(cr[1] + gr[1] + bhr[1]);
                const float z1 = fast_sig(cz[1] + gz[1] + bhz[1]);
                const float n1 = fast_tanh(cn[1] + r1 * (gn[1] + bhn[1]));
                hv1 = (1.f - z1) * n1 + z1 * h1;
                const float r2 = fast_sig(cr[2] + gr[2] + bhr[2]);
                const float z2 = fast_sig(cz[2] + gz[2] + bhz[2]);
                const float n2 = fast_tanh(cn[2] + r2 * (gn[2] + bhn[2]));
                hv2 = (1.f - z2) * n2 + z2 * h2;
                const float r3 = fast_sig(cr[3] + gr[3] + bhr[3]);
                const float z3 = fast_sig(cz[3] + gz[3] + bhz[3]);
                const float n3 = fast_tanh(cn[3] + r3 * (gn[3] + bhn[3]));
                hv3 = (1.f - z3) * n3 + z3 * h3;
            }
            h0 = hv0; h1 = hv1; h2 = hv2; h3 = hv3;
            us4_t hp;
            { __hip_bfloat16 t0 = __float2bfloat16(h0); hp[0] = *(ushort_t*)&t0; }
            { __hip_bfloat16 t1 = __float2bfloat16(h1); hp[1] = *(ushort_t*)&t1; }
            { __hip_bfloat16 t2 = __float2bfloat16(h2); hp[2] = *(ushort_t*)&t2; }
            { __hip_bfloat16 t3 = __float2bfloat16(h3); hp[3] = *(ushort_t*)&t3; }
            *(us4_t*)&g->hb[b * 136 + hh0] = hp;
            cr = nr; cz = nz; cn = nn;
            __syncthreads();
        }
        f32x4 ho = {h0, h1, h2, h3};
        *(f32x4*)&hlast[b * HID + hh0] = ho;
        return;
    }

    // ======================= CNN branch, one image per block =======================
    ConvS* c = (ConvS*)smraw;
    const int img = bid - 1;
    const float* xim = x_img + (size_t)img * (IH * IW);

    // zero the xs=0 / xs=31 halo columns of pool1t
    if (tid < 256) {
        const int y = tid >> 3, cg = (tid >> 1) & 3, xs = (tid & 1) * 31;
        short8_t z = {0, 0, 0, 0, 0, 0, 0, 0};
        *(short8_t*)&c->pool1t[y][cg][xs][0] = z;
    }
    // copy image to LDS (float4)
    {
        const f32x4* src = (const f32x4*)xim;
        f32x4* dst = (f32x4*)c->u.imgp;
        for (int i = tid; i < 960; i += 512) dst[i] = src[i];
    }
    __syncthreads();

    // ---- conv1+relu+pool1: thread = pooled position; channel loop, uniform weights ----
    #pragma unroll
    for (int rep = 0; rep < 2; ++rep) {
        const int p = tid + rep * 512;
        if (p < 960) {
            const int py = p / 30, px = p - py * 30;
            float patch[4][4];
            #pragma unroll
            for (int yy = 0; yy < 4; ++yy) {
                const int iy = 2 * py - 1 + yy;
                #pragma unroll
                for (int xx = 0; xx < 4; ++xx) {
                    const int ix = 2 * px - 1 + xx;
                    patch[yy][xx] = (iy >= 0 && iy < IH && ix >= 0 && ix < IW)
                                        ? c->u.imgp[iy][ix] : 0.f;
                }
            }
            #pragma unroll
            for (int cg = 0; cg < 4; ++cg) {
                short8_t outv;
                #pragma unroll
                for (int ch8 = 0; ch8 < 8; ++ch8) {
                    const int ch = cg * 8 + ch8;
                    float wr[9];
                    #pragma unroll
                    for (int q = 0; q < 9; ++q) wr[q] = c1w[ch * 9 + q];   // wave-uniform -> SGPR
                    const float bia = c1b[ch];
                    float best = 0.f;
                    #pragma unroll
                    for (int dy = 0; dy < 2; ++dy)
                        #pragma unroll
                        for (int dx = 0; dx < 2; ++dx) {
                            float sv = 0.f;
                            #pragma unroll
                            for (int ky = 0; ky < 3; ++ky)
                                #pragma unroll
                                for (int kx = 0; kx < 3; ++kx)
                                    sv = fmaf(patch[dy + ky][dx + kx], wr[ky * 3 + kx], sv);
                            best = fmaxf(best, sv + bia);
                        }
                    __hip_bfloat16 hv = __float2bfloat16(best);
                    outv[ch8] = *(short*)&hv;
                }
                *(short8_t*)&c->pool1t[py][cg][px + 1][0] = outv;
            }
        }
    }
    __syncthreads();   // conv1 done; imgp is now dead -> pool2s may reuse it

    // ---- conv2 via bf16 MFMA 32x32x16 implicit GEMM; two staged half-tiles ----
    {
        const int w  = tid >> 6, l = tid & 63;
        const int m  = w & 1;
        const int hi = l >> 5;
        const int col = l & 31;

        short8_t af[9][2];
        #pragma unroll
        for (int tap = 0; tap < 9; ++tap)
            #pragma unroll
            for (int ks = 0; ks < 2; ++ks)
                af[tap][ks] = *(const short8_t*)&wprep[(((m * 9 + tap) * 2 + ks) * 64 + l) * 8];
        float bia[16];
        #pragma unroll
        for (int r = 0; r < 16; ++r)
            bia[r] = c2b[m * 32 + (r & 3) + 8 * (r >> 2) + 4 * hi];

        const bool wr = ((col & 1) == 0) && (col < 30);
        const int px = col >> 1;
        const short8_t bfz = {0, 0, 0, 0, 0, 0, 0, 0};

        #pragma unroll
        for (int ph = 0; ph < 2; ++ph) {
            #pragma unroll
            for (int yy = 0; yy < 2; ++yy) {
                const int yp = ph * 8 + (w >> 1) + yy * 4;
                f32x16 a0, a1;
                #pragma unroll
                for (int r = 0; r < 16; ++r) { a0[r] = 0.f; a1[r] = 0.f; }
                #pragma unroll
                for (int ro = 0; ro < 4; ++ro) {
                    const int y = 2 * yp - 1 + ro;
                    short8_t bf[3][2];
                    if (y >= 0 && y < 32) {     // wave-uniform
                        #pragma unroll
                        for (int kx = 0; kx < 3; ++kx)
                            #pragma unroll
                            for (int ks = 0; ks < 2; ++ks)
                                bf[kx][ks] = *(const short8_t*)&c->pool1t[y][ks * 2 + hi][kx + col][0];
                    } else {
                        #pragma unroll
                        for (int kx = 0; kx < 3; ++kx)
                            #pragma unroll
                            for (int ks = 0; ks < 2; ++ks) bf[kx][ks] = bfz;
                    }
                    if (ro < 3) {
                        #pragma unroll
                        for (int kx = 0; kx < 3; ++kx)
                            #pragma unroll
                            for (int ks = 0; ks < 2; ++ks)
                                a0 = __builtin_amdgcn_mfma_f32_32x32x16_bf16(af[ro * 3 + kx][ks], bf[kx][ks], a0, 0, 0, 0);
                    }
                    if (ro >= 1) {
                        #pragma unroll
                        for (int kx = 0; kx < 3; ++kx)
                            #pragma unroll
                            for (int ks = 0; ks < 2; ++ks)
                                a1 = __builtin_amdgcn_mfma_f32_32x32x16_bf16(af[(ro - 1) * 3 + kx][ks], bf[kx][ks], a1, 0, 0, 0);
                    }
                }
                #pragma unroll
                for (int r = 0; r < 16; ++r) {
                    float v = fmaxf(a0[r], a1[r]);
                    v = fmaxf(v, __shfl_xor(v, 1, 64));
                    v = fmaxf(v + bia[r], 0.f);
                    if (wr) {
                        const int oc = m * 32 + (r & 3) + 8 * (r >> 2) + 4 * hi;
                        __hip_bfloat16 hv = __float2bfloat16(v);
                        c->u.pool2s[oc][(yp & 7) * 15 + px] = *(ushort_t*)&hv;
                    }
                }
            }
            __syncthreads();   // staging complete
            // coalesced flush: 960 int4 = 64 oc rows x 15 int4 (120 ushorts each)
            {
                int4* dst = (int4*)(pool2 + (size_t)img * FCIN);
                const int4* src = (const int4*)c->u.pool2s;
                #pragma unroll
                for (int jj = 0; jj < 2; ++jj) {
                    const int i = tid + jj * 512;
                    if (i < 960) {
                        const int oc = i / 15, cc = i - oc * 15;
                        dst[oc * 30 + ph * 15 + cc] = src[i];
                    }
                }
            }
            __syncthreads();   // flush done before next phase overwrites staging
        }
    }
}

// -------- fc1 (full-K MFMA, 8 waves: 2 K-halves x 4 oc-tiles) + heads --------
__global__ __launch_bounds__(512) void k_fc1post(const ushort_t* __restrict__ pool2,
                                                 const ushort_t* __restrict__ wfc1,
                                                 const float* __restrict__ fc1b,
                                                 const float* __restrict__ fbw,
                                                 const float* __restrict__ fbb,
                                                 const float* __restrict__ fc2w,
                                                 const float* __restrict__ fc2b,
                                                 float* __restrict__ out,
                                                 float* __restrict__ fc2o)
{
    const int mt = blockIdx.x;                  // 0..49, 16 images each
    const int w = threadIdx.x >> 6, l = threadIdx.x & 63;
    const int kh = w >> 2;                      // K-half (0: k<7680, 1: k>=7680)
    const int n  = w & 3;                       // oc tile (16 oc)
    const int arow = l & 15, kq = l >> 4;
    const int img16 = mt * 16;
    const ushort_t* Ab = pool2 + (size_t)(img16 + arow) * FCIN + kh * 7680 + kq * 8;
    const ushort_t* Bb = wfc1 + (size_t)kh * 491520 + (size_t)n * 512 + (size_t)l * 8;
    f32x4 acc0 = {0.f, 0.f, 0.f, 0.f}, acc1 = {0.f, 0.f, 0.f, 0.f};
    #pragma unroll 4
    for (int T = 0; T < 240; T += 2) {
        const short8_t aA = *(const short8_t*)(Ab + (size_t)T * 32);
        const short8_t bA = *(const short8_t*)(Bb + (size_t)T * 2048);
        const short8_t aB = *(const short8_t*)(Ab + (size_t)(T + 1) * 32);
        const short8_t bB = *(const short8_t*)(Bb + (size_t)(T + 1) * 2048);
        acc0 = __builtin_amdgcn_mfma_f32_16x16x32_bf16(aA, bA, acc0, 0, 0, 0);
        acc1 = __builtin_amdgcn_mfma_f32_16x16x32_bf16(aB, bB, acc1, 0, 0, 0);
    }
    __shared__ float fl[2][16][64];
    __shared__ float flc[16][64];
    const int oc = n * 16 + arow;
    #pragma unroll
    for (int r = 0; r < 4; ++r)
        fl[kh][kq * 4 + r][oc] = acc0[r] + acc1[r];
    __syncthreads();

    const int t = threadIdx.x;
    // combine K-halves + bias + relu
    #pragma unroll
    for (int q = 0; q < 2; ++q) {
        const int idx = t + q * 512;
        const int im = idx >> 6, o = idx & 63;
        flc[im][o] = fmaxf(fl[0][im][o] + fl[1][im][o] + fc1b[o], 0.f);
    }
    __syncthreads();

    const int im = t >> 5, tl = t & 31;          // 32 threads per image
    // binary head
    float bs = flc[im][tl * 2] * fbw[tl * 2] + flc[im][tl * 2 + 1] * fbw[tl * 2 + 1];
    bs += __shfl_xor(bs, 1, 64);  bs += __shfl_xor(bs, 2, 64);
    bs += __shfl_xor(bs, 4, 64);  bs += __shfl_xor(bs, 8, 64);
    bs += __shfl_xor(bs, 16, 64);
    if (tl == 0) out[800 + img16 + im] = 1.f / (1.f + expf(-(bs + fbb[0])));
    // fc2
    #pragma unroll
    for (int q = 0; q < 4; ++q) {
        const int j = tl + q * 32;
        float a2 = fc2b[j];
        #pragma unroll 8
        for (int k = 0; k < 64; ++k) a2 = fmaf(flc[im][k], fc2w[j * 64 + k], a2);
        fc2o[(size_t)(img16 + im) * 128 + j] = a2;
    }
}

__device__ __forceinline__ float wave_sum(float v) {
    #pragma unroll
    for (int o = 32; o > 0; o >>= 1) v += __shfl_xor(v, o, 64);
    return v;
}
__device__ __forceinline__ float wave_max(float v) {
    #pragma unroll
    for (int o = 32; o > 0; o >>= 1) v = fmaxf(v, __shfl_xor(v, o, 64));
    return v;
}

// ---------------- fusion + softmax + 32-iter water-filling rebalance --------
__global__ __launch_bounds__(64) void k_final(const float* __restrict__ hlast,
                                              const float* __restrict__ fc2o,
                                              const float* __restrict__ gw,
                                              const float* __restrict__ gb,
                                              const float* __restrict__ fw,
                                              const float* __restrict__ fb,
                                              const float* __restrict__ finw,
                                              const float* __restrict__ finb,
                                              float* __restrict__ out)
{
    const int b = blockIdx.x, t = threadIdx.x;
    __shared__ float cf[128], nf[64], fu[64];
    #pragma unroll
    for (int jj = 0; jj < 2; ++jj) {
        const int j = t + jj * 64;
        float s = 0.f;
        for (int n = 0; n < NSTK; ++n) s += fc2o[(size_t)(b * NSTK + n) * 128 + j];
        cf[j] = s * (1.0f / 50.0f);
    }
    float s = 0.f;
    if (t < NSTK) {
        s = gb[t];
        for (int k = 0; k < HID; ++k) s = fmaf(hlast[b * HID + k], gw[t * HID + k], s);
    }
    nf[t] = (t < NSTK) ? s : 0.f;
    __syncthreads();
    float f = fb[t];
    for (int k = 0; k < NSTK; ++k) f = fmaf(nf[k], fw[t * 178 + k], f);
    for (int k = 0; k < 128; ++k) f = fmaf(cf[k], fw[t * 178 + 50 + k], f);
    fu[t] = fmaxf(f, 0.f);
    __syncthreads();
    float L = -3.4e38f;
    if (t < NSTK) {
        L = finb[t];
        for (int k = 0; k < 64; ++k) L = fmaf(fu[k], finw[t * 64 + k], L);
    }
    const float m = wave_max(L);
    const float e = (t < NSTK) ? expf(L - m) : 0.f;
    const float se = wave_sum(e);
    const float wv = e / se;
    float old = wv;
    float wc = fminf(fmaxf(wv, 0.f), 0.1f);
    for (int it = 0; it < 32; ++it) {
        const float leftover = wave_sum(old - wc);
        const bool mask = (wc != 0.1f);
        const float ssum = wave_sum(mask ? wc : 0.f);
        const float gift = (mask && ssum > 0.f) ? leftover * wc / ssum : 0.f;
        old = wc + gift;
        wc = fminf(fmaxf(old, 0.f), 0.1f);
    }
    if (t < NSTK) out[b * NSTK + t] = wc;
}

// ---------------------------------------------------------------------------
extern "C" void kernel_launch(void* const* d_in, const int* in_sizes, int n_in,
                              void* d_out, int out_size, void* d_ws, size_t ws_size,
                              hipStream_t stream)
{
    const float* x_num = (const float*)d_in[0];
    const float* x_img = (const float*)d_in[1];
    const float* c1w  = (const float*)d_in[2];
    const float* c1b  = (const float*)d_in[3];
    const float* c2w  = (const float*)d_in[4];
    const float* c2b  = (const float*)d_in[5];
    const float* fc1w = (const float*)d_in[6];
    const float* fc1b = (const float*)d_in[7];
    const float* fbw  = (const float*)d_in[8];
    const float* fbb  = (const float*)d_in[9];
    const float* fc2w = (const float*)d_in[10];
    const float* fc2b = (const float*)d_in[11];
    const float* wih  = (const float*)d_in[12];
    const float* whh  = (const float*)d_in[13];
    const float* bih  = (const float*)d_in[14];
    const float* bhh  = (const float*)d_in[15];
    const float* gw   = (const float*)d_in[16];
    const float* gb   = (const float*)d_in[17];
    const float* fw   = (const float*)d_in[18];
    const float* fb   = (const float*)d_in[19];
    const float* finw = (const float*)d_in[20];
    const float* finb = (const float*)d_in[21];
    float* out = (float*)d_out;
    float* ws  = (float*)d_ws;
    if (ws_size < (size_t)WS_FLOATS * 4) return;

    ushort_t* whhf  = (ushort_t*)(ws + OFF_WHHF);
    ushort_t* wprep = (ushort_t*)(ws + OFF_WPREP);
    ushort_t* wfc1  = (ushort_t*)(ws + OFF_WFC1);
    float* GI       = ws + OFF_GI;
    float* hlast    = ws + OFF_HLAST;
    ushort_t* pool2 = (ushort_t*)(ws + OFF_POOL2);
    float* fc2o     = ws + OFF_FC2O;

    (void)hipFuncSetAttribute(reinterpret_cast<const void*>(k_mega),
                              hipFuncAttributeMaxDynamicSharedMemorySize, SMEM_BYTES);

    k_pre    <<<960 + 2736, 384, 0, stream>>>(x_num, wih, bih, whh, c2w, fc1w,
                                              GI, whhf, wprep, wfc1);
    k_mega   <<<NIMG + 1, 512, SMEM_BYTES, stream>>>(x_img, c1w, c1b, c2b, wprep,
                                                     GI, whhf, bhh, pool2, hlast);
    k_fc1post<<<50, 512, 0, stream>>>(pool2, wfc1, fc1b, fbw, fbb, fc2w, fc2b, out, fc2o);
    k_final  <<<NBATCH, 64, 0, stream>>>(hlast, fc2o, gw, gb, fw, fb, finw, finb, out);
}

// Round 6
// 153.817 us; speedup vs baseline: 1.9062x; 1.4820x over previous
//
#include <hip/hip_runtime.h>
#include <hip/hip_bf16.h>

typedef unsigned short ushort_t;
typedef short short8_t __attribute__((ext_vector_type(8)));
typedef float f32x4 __attribute__((ext_vector_type(4)));
typedef float f32x16 __attribute__((ext_vector_type(16)));
typedef ushort_t us4_t __attribute__((ext_vector_type(4)));

#define NBATCH 16
#define SEQ    60
#define NSTK   50
#define HID    128
#define G3     384
#define NIMG   800
#define IH     64
#define IW     60
#define P1H    32
#define P1W    30
#define P2C    64
#define FCIN   15360

// ---- workspace layout (float offsets) ----
#define OFF_WHHF   0u          // 49152 ushort  = 24576 f
#define OFF_WPREP  24576u      // 18432 ushort  = 9216 f
#define OFF_WFC1   33792u      // 983040 ushort = 491520 f
#define OFF_GI     525312u     // 368640 f
#define OFF_HLAST  893952u     // 2048 f
#define OFF_POOL2  896000u     // 800*15360 bf16 = 6144000 f
#define OFF_FC2O   7040000u    // 102400 f
#define OFF_PART   7142400u    // 16*800*64 = 819200 f
#define WS_FLOATS  7961600u    // ~31.8 MB

// swizzle element counts for k_pre
#define E_WHH  49152
#define E_WPR  18432
#define E_FC1  983040
#define E_TOT  (E_WHH + E_WPR + E_FC1)   // 1050624 = 2736*384

// ---------------- shared-memory layouts for the mega kernel ----------------
struct __align__(16) ConvS {
    ushort_t pool1t[32][4][32][8];     // 65536 B  [y][cg][xs][ch8], xs=x+1; xs 0,31 zeroed
    union {
        float    imgp[64][60];         // 15360 B  (conv1 phase)
        ushort_t pool2s[64][120];      // 15360 B  (conv2 half-tile staging)
    } u;
};                                      // 80896 B  -> 2 blocks/CU
struct __align__(16) GruS {
    float    gh[16 * 388];             // 24832 B
    ushort_t hb[16 * 136];             //  4352 B
};                                      // 29184 B
#define SMEM_BYTES 80896

__device__ __forceinline__ float fast_sig(float x) {
    const float e = __expf(-x);
    return __builtin_amdgcn_rcpf(1.f + e);
}
__device__ __forceinline__ float fast_tanh(float x) {
    const float xc = fmaxf(fminf(x, 15.f), -15.f);
    const float e = __expf(2.f * xc);
    return (e - 1.f) * __builtin_amdgcn_rcpf(e + 1.f);
}

// ---------------- k_pre: GI (blocks 0..959) + weight swizzles (960..) ----------------
__global__ __launch_bounds__(384) void k_pre(const float* __restrict__ xnum,
                                             const float* __restrict__ wih,
                                             const float* __restrict__ bih,
                                             const float* __restrict__ whh,
                                             const float* __restrict__ c2w,
                                             const float* __restrict__ fc1w,
                                             float* __restrict__ GI,
                                             ushort_t* __restrict__ whhf,
                                             ushort_t* __restrict__ wprep,
                                             ushort_t* __restrict__ wfc1)
{
    const int bid = blockIdx.x;
    if (bid < 960) {
        const int s = bid >> 4, b = bid & 15;
        const int j = threadIdx.x;
        const float* xr = xnum + (size_t)(b * SEQ + s) * NSTK;   // wave-uniform -> scalar loads
        const float* wr = wih + (size_t)j * NSTK;
        float a = bih[j];
        #pragma unroll 10
        for (int k = 0; k < NSTK; ++k) a = fmaf(xr[k], wr[k], a);
        GI[((size_t)s * 16 + b) * G3 + j] = a;
        return;
    }
    const int idx = (bid - 960) * 384 + threadIdx.x;
    if (idx < E_WHH) {
        const int e = idx;                  // (((jt*4+ks)*64 + l)*8 + i)
        const int i = e & 7, l = (e >> 3) & 63, ksj = e >> 9;
        const int ks = ksj & 3, jt = ksj >> 2;
        const int j = jt * 16 + (l & 15);
        const int k = ks * 32 + ((l >> 4) << 3) + i;
        __hip_bfloat16 hv = __float2bfloat16(whh[j * HID + k]);
        whhf[e] = *(ushort_t*)&hv;
    } else if (idx < E_WHH + E_WPR) {
        const int e = idx - E_WHH;          // (((m*9+tap)*2+ks)*64 + l)*8 + i
        const int i = e & 7, l = (e >> 3) & 63, rest = e >> 9;
        const int ks = rest & 1, mt = rest >> 1;
        const int tap = mt % 9, mm = mt / 9;
        const int oc = mm * 32 + (l & 31);
        const int ic = ks * 16 + ((l >> 5) << 3) + i;
        __hip_bfloat16 hv = __float2bfloat16(c2w[((size_t)oc * 32 + ic) * 9 + tap]);
        wprep[e] = *(ushort_t*)&hv;
    } else if (idx < E_TOT) {
        const int e = idx - (E_WHH + E_WPR); // ((T*4+n)*64 + l)*8 + i
        const int i = e & 7, l = (e >> 3) & 63, rest = e >> 9;
        const int n = rest & 3, T = rest >> 2;
        const int oc = n * 16 + (l & 15);
        const int k = T * 32 + ((l >> 4) << 3) + i;
        __hip_bfloat16 hv = __float2bfloat16(fc1w[(size_t)oc * FCIN + k]);
        wfc1[e] = *(ushort_t*)&hv;
    }
}

// ---------------- mega kernel: block 0 = GRU, blocks 1..800 = one image each ----
__global__ __launch_bounds__(512, 2) void k_mega(const float* __restrict__ x_img,
                                                 const float* __restrict__ c1w,
                                                 const float* __restrict__ c1b,
                                                 const float* __restrict__ c2b,
                                                 const ushort_t* __restrict__ wprep,
                                                 const float* __restrict__ GI,
                                                 const ushort_t* __restrict__ whhf,
                                                 const float* __restrict__ bhh,
                                                 ushort_t* __restrict__ pool2,
                                                 float* __restrict__ hlast)
{
    extern __shared__ char smraw[];
    const int tid = threadIdx.x;
    const int bid = blockIdx.x;

    if (bid == 0) {
        // =========== GRU: W_hh frags in regs, GI prefetch, h in regs ===========
        GruS* g = (GruS*)smraw;
        const int w = tid >> 6, l = tid & 63;
        const int arow = l & 15, kq = l >> 4;
        short8_t wfr[3][4];
        #pragma unroll
        for (int jj = 0; jj < 3; ++jj)
            #pragma unroll
            for (int ks = 0; ks < 4; ++ks)
                wfr[jj][ks] = *(const short8_t*)&whhf[((((w * 3 + jj) * 4 + ks) * 64 + l) * 8)];

        const int b = tid >> 5, hh0 = (tid & 31) * 4;
        const f32x4 bhr = *(const f32x4*)&bhh[hh0];
        const f32x4 bhz = *(const f32x4*)&bhh[128 + hh0];
        const f32x4 bhn = *(const f32x4*)&bhh[256 + hh0];
        float h0 = 0.f, h1 = 0.f, h2 = 0.f, h3 = 0.f;
        for (int i = tid; i < 1088; i += 512) ((unsigned int*)g->hb)[i] = 0u;
        const float* gi0 = GI + b * G3 + hh0;
        f32x4 cr = *(const f32x4*)(gi0);
        f32x4 cz = *(const f32x4*)(gi0 + 128);
        f32x4 cn = *(const f32x4*)(gi0 + 256);
        __syncthreads();

        for (int s = 0; s < SEQ; ++s) {
            const int sn = (s + 1 < SEQ) ? s + 1 : s;
            const float* gnx = GI + ((size_t)sn * 16 + b) * G3 + hh0;
            const f32x4 nr = *(const f32x4*)(gnx);
            const f32x4 nz = *(const f32x4*)(gnx + 128);
            const f32x4 nn = *(const f32x4*)(gnx + 256);

            #pragma unroll
            for (int jj = 0; jj < 3; ++jj) {
                f32x4 a = {0.f, 0.f, 0.f, 0.f};
                #pragma unroll
                for (int ks = 0; ks < 4; ++ks) {
                    short8_t af = *(const short8_t*)&g->hb[arow * 136 + ks * 32 + kq * 8];
                    a = __builtin_amdgcn_mfma_f32_16x16x32_bf16(af, wfr[jj][ks], a, 0, 0, 0);
                }
                const int jt = w * 3 + jj;
                #pragma unroll
                for (int r = 0; r < 4; ++r)
                    g->gh[(kq * 4 + r) * 388 + jt * 16 + arow] = a[r];
            }
            __syncthreads();

            const f32x4 gr = *(const f32x4*)&g->gh[b * 388 + hh0];
            const f32x4 gz = *(const f32x4*)&g->gh[b * 388 + 128 + hh0];
            const f32x4 gn = *(const f32x4*)&g->gh[b * 388 + 256 + hh0];
            float hv0, hv1, hv2, hv3;
            {
                const float r0 = fast_sig(cr[0] + gr[0] + bhr[0]);
                const float z0 = fast_sig(cz[0] + gz[0] + bhz[0]);
                const float n0 = fast_tanh(cn[0] + r0 * (gn[0] + bhn[0]));
                hv0 = (1.f - z0) * n0 + z0 * h0;
                const float r1 = fast_sig(cr[1] + gr[1] + bhr[1]);
                const float z1 = fast_sig(cz[1] + gz[1] + bhz[1]);
                const float n1 = fast_tanh(cn[1] + r1 * (gn[1] + bhn[1]));
                hv1 = (1.f - z1) * n1 + z1 * h1;
                const float r2 = fast_sig(cr[2] + gr[2] + bhr[2]);
                const float z2 = fast_sig(cz[2] + gz[2] + bhz[2]);
                const float n2 = fast_tanh(cn[2] + r2 * (gn[2] + bhn[2]));
                hv2 = (1.f - z2) * n2 + z2 * h2;
                const float r3 = fast_sig(cr[3] + gr[3] + bhr[3]);
                const float z3 = fast_sig(cz[3] + gz[3] + bhz[3]);
                const float n3 = fast_tanh(cn[3] + r3 * (gn[3] + bhn[3]));
                hv3 = (1.f - z3) * n3 + z3 * h3;
            }
            h0 = hv0; h1 = hv1; h2 = hv2; h3 = hv3;
            us4_t hp;
            { __hip_bfloat16 t0 = __float2bfloat16(h0); hp[0] = *(ushort_t*)&t0; }
            { __hip_bfloat16 t1 = __float2bfloat16(h1); hp[1] = *(ushort_t*)&t1; }
            { __hip_bfloat16 t2 = __float2bfloat16(h2); hp[2] = *(ushort_t*)&t2; }
            { __hip_bfloat16 t3 = __float2bfloat16(h3); hp[3] = *(ushort_t*)&t3; }
            *(us4_t*)&g->hb[b * 136 + hh0] = hp;
            cr = nr; cz = nz; cn = nn;
            __syncthreads();
        }
        f32x4 ho = {h0, h1, h2, h3};
        *(f32x4*)&hlast[b * HID + hh0] = ho;
        return;
    }

    // ======================= CNN branch, one image per block =======================
    ConvS* c = (ConvS*)smraw;
    const int img = bid - 1;
    const float* xim = x_img + (size_t)img * (IH * IW);

    // zero the xs=0 / xs=31 halo columns of pool1t
    if (tid < 256) {
        const int y = tid >> 3, cg = (tid >> 1) & 3, xs = (tid & 1) * 31;
        short8_t z = {0, 0, 0, 0, 0, 0, 0, 0};
        *(short8_t*)&c->pool1t[y][cg][xs][0] = z;
    }
    // copy image to LDS (float4)
    {
        const f32x4* src = (const f32x4*)xim;
        f32x4* dst = (f32x4*)c->u.imgp;
        for (int i = tid; i < 960; i += 512) dst[i] = src[i];
    }
    __syncthreads();

    // ---- conv1+relu+pool1: thread = pooled position; channel loop, uniform weights ----
    #pragma unroll
    for (int rep = 0; rep < 2; ++rep) {
        const int p = tid + rep * 512;
        if (p < 960) {
            const int py = p / 30, px = p - py * 30;
            float patch[4][4];
            #pragma unroll
            for (int yy = 0; yy < 4; ++yy) {
                const int iy = 2 * py - 1 + yy;
                #pragma unroll
                for (int xx = 0; xx < 4; ++xx) {
                    const int ix = 2 * px - 1 + xx;
                    patch[yy][xx] = (iy >= 0 && iy < IH && ix >= 0 && ix < IW)
                                        ? c->u.imgp[iy][ix] : 0.f;
                }
            }
            #pragma unroll
            for (int cg = 0; cg < 4; ++cg) {
                short8_t outv;
                #pragma unroll
                for (int ch8 = 0; ch8 < 8; ++ch8) {
                    const int ch = cg * 8 + ch8;
                    float wr[9];
                    #pragma unroll
                    for (int q = 0; q < 9; ++q) wr[q] = c1w[ch * 9 + q];   // wave-uniform -> SGPR
                    const float bia = c1b[ch];
                    float best = 0.f;
                    #pragma unroll
                    for (int dy = 0; dy < 2; ++dy)
                        #pragma unroll
                        for (int dx = 0; dx < 2; ++dx) {
                            float sv = 0.f;
                            #pragma unroll
                            for (int ky = 0; ky < 3; ++ky)
                                #pragma unroll
                                for (int kx = 0; kx < 3; ++kx)
                                    sv = fmaf(patch[dy + ky][dx + kx], wr[ky * 3 + kx], sv);
                            best = fmaxf(best, sv + bia);
                        }
                    __hip_bfloat16 hv = __float2bfloat16(best);
                    outv[ch8] = *(short*)&hv;
                }
                *(short8_t*)&c->pool1t[py][cg][px + 1][0] = outv;
            }
        }
    }
    __syncthreads();   // conv1 done; imgp is now dead -> pool2s may reuse it

    // ---- conv2 via bf16 MFMA 32x32x16 implicit GEMM; two staged half-tiles ----
    {
        const int w  = tid >> 6, l = tid & 63;
        const int m  = w & 1;
        const int hi = l >> 5;
        const int col = l & 31;

        short8_t af[9][2];
        #pragma unroll
        for (int tap = 0; tap < 9; ++tap)
            #pragma unroll
            for (int ks = 0; ks < 2; ++ks)
                af[tap][ks] = *(const short8_t*)&wprep[(((m * 9 + tap) * 2 + ks) * 64 + l) * 8];
        float bia[16];
        #pragma unroll
        for (int r = 0; r < 16; ++r)
            bia[r] = c2b[m * 32 + (r & 3) + 8 * (r >> 2) + 4 * hi];

        const bool wr = ((col & 1) == 0) && (col < 30);
        const int px = col >> 1;
        const short8_t bfz = {0, 0, 0, 0, 0, 0, 0, 0};

        #pragma unroll
        for (int ph = 0; ph < 2; ++ph) {
            #pragma unroll
            for (int yy = 0; yy < 2; ++yy) {
                const int yp = ph * 8 + (w >> 1) + yy * 4;
                f32x16 a0, a1;
                #pragma unroll
                for (int r = 0; r < 16; ++r) { a0[r] = 0.f; a1[r] = 0.f; }
                #pragma unroll
                for (int ro = 0; ro < 4; ++ro) {
                    const int y = 2 * yp - 1 + ro;
                    short8_t bf[3][2];
                    if (y >= 0 && y < 32) {     // wave-uniform
                        #pragma unroll
                        for (int kx = 0; kx < 3; ++kx)
                            #pragma unroll
                            for (int ks = 0; ks < 2; ++ks)
                                bf[kx][ks] = *(const short8_t*)&c->pool1t[y][ks * 2 + hi][kx + col][0];
                    } else {
                        #pragma unroll
                        for (int kx = 0; kx < 3; ++kx)
                            #pragma unroll
                            for (int ks = 0; ks < 2; ++ks) bf[kx][ks] = bfz;
                    }
                    if (ro < 3) {
                        #pragma unroll
                        for (int kx = 0; kx < 3; ++kx)
                            #pragma unroll
                            for (int ks = 0; ks < 2; ++ks)
                                a0 = __builtin_amdgcn_mfma_f32_32x32x16_bf16(af[ro * 3 + kx][ks], bf[kx][ks], a0, 0, 0, 0);
                    }
                    if (ro >= 1) {
                        #pragma unroll
                        for (int kx = 0; kx < 3; ++kx)
                            #pragma unroll
                            for (int ks = 0; ks < 2; ++ks)
                                a1 = __builtin_amdgcn_mfma_f32_32x32x16_bf16(af[(ro - 1) * 3 + kx][ks], bf[kx][ks], a1, 0, 0, 0);
                    }
                }
                #pragma unroll
                for (int r = 0; r < 16; ++r) {
                    float v = fmaxf(a0[r], a1[r]);
                    v = fmaxf(v, __shfl_xor(v, 1, 64));
                    v = fmaxf(v + bia[r], 0.f);
                    if (wr) {
                        const int oc = m * 32 + (r & 3) + 8 * (r >> 2) + 4 * hi;
                        __hip_bfloat16 hv = __float2bfloat16(v);
                        c->u.pool2s[oc][(yp & 7) * 15 + px] = *(ushort_t*)&hv;
                    }
                }
            }
            __syncthreads();   // staging complete
            // coalesced flush: 960 int4 = 64 oc rows x 15 int4 (120 ushorts each)
            {
                int4* dst = (int4*)(pool2 + (size_t)img * FCIN);
                const int4* src = (const int4*)c->u.pool2s;
                #pragma unroll
                for (int jj = 0; jj < 2; ++jj) {
                    const int i = tid + jj * 512;
                    if (i < 960) {
                        const int oc = i / 15, cc = i - oc * 15;
                        dst[oc * 30 + ph * 15 + cc] = src[i];
                    }
                }
            }
            __syncthreads();   // flush done before next phase overwrites staging
        }
    }
}

// -------- fc1 split-K MFMA: 50 M-tiles x 16 K-splits, part[ks][img][oc] --------
__global__ __launch_bounds__(256) void k_fc1(const ushort_t* __restrict__ pool2,
                                             const ushort_t* __restrict__ wfc1,
                                             float* __restrict__ part)
{
    const int mt = blockIdx.x >> 4;             // 0..49 (16 images)
    const int ks = blockIdx.x & 15;             // K-split of 960
    const int n = threadIdx.x >> 6, l = threadIdx.x & 63;   // wave = oc tile
    const int arow = l & 15, kq = l >> 4;
    const int img16 = mt * 16;
    const ushort_t* Ab = pool2 + (size_t)(img16 + arow) * FCIN + ks * 960 + kq * 8;
    const ushort_t* Bb = wfc1 + ((size_t)(ks * 30 * 4 + n) * 64 + l) * 8;
    f32x4 acc0 = {0.f, 0.f, 0.f, 0.f}, acc1 = {0.f, 0.f, 0.f, 0.f};
    #pragma unroll 5
    for (int t = 0; t < 30; t += 2) {
        const short8_t aA = *(const short8_t*)(Ab + (size_t)t * 32);
        const short8_t bA = *(const short8_t*)(Bb + (size_t)t * 2048);
        const short8_t aB = *(const short8_t*)(Ab + (size_t)(t + 1) * 32);
        const short8_t bB = *(const short8_t*)(Bb + (size_t)(t + 1) * 2048);
        acc0 = __builtin_amdgcn_mfma_f32_16x16x32_bf16(aA, bA, acc0, 0, 0, 0);
        acc1 = __builtin_amdgcn_mfma_f32_16x16x32_bf16(aB, bB, acc1, 0, 0, 0);
    }
    // D: row (image) = kq*4+r, col (oc-in-tile) = arow
    float* dst = &part[((size_t)ks * NIMG + img16 + kq * 4) * 64 + n * 16 + arow];
    #pragma unroll
    for (int r = 0; r < 4; ++r)
        dst[(size_t)r * 64] = acc0[r] + acc1[r];
}

__device__ __forceinline__ float wave_sum(float v) {
    #pragma unroll
    for (int o = 32; o > 0; o >>= 1) v += __shfl_xor(v, o, 64);
    return v;
}
__device__ __forceinline__ float wave_max(float v) {
    #pragma unroll
    for (int o = 32; o > 0; o >>= 1) v = fmaxf(v, __shfl_xor(v, o, 64));
    return v;
}

// -------- reduce fc1 partials + relu + binary head + fc2 (8 imgs/block) --------
__global__ __launch_bounds__(512) void k_post(const float* __restrict__ part,
                                              const float* __restrict__ fc1b,
                                              const float* __restrict__ fbw,
                                              const float* __restrict__ fbb,
                                              const float* __restrict__ fc2w,
                                              const float* __restrict__ fc2b,
                                              float* __restrict__ out,
                                              float* __restrict__ fc2o)
{
    const int t = threadIdx.x;
    const int im8 = t >> 6;                     // 0..7 == wave id
    const int tl = t & 63;                      // oc
    const int img = blockIdx.x * 8 + im8;
    float s = fc1b[tl];
    #pragma unroll
    for (int ks = 0; ks < 16; ++ks) s += part[((size_t)ks * NIMG + img) * 64 + tl];
    const float f = fmaxf(s, 0.f);
    __shared__ float flc[8][64];
    flc[im8][tl] = f;
    const float bs = wave_sum(f * fbw[tl]);
    if (tl == 0) out[800 + img] = 1.f / (1.f + expf(-(bs + fbb[0])));
    __syncthreads();
    #pragma unroll
    for (int q = 0; q < 2; ++q) {
        const int j = tl + q * 64;
        float a2 = fc2b[j];
        #pragma unroll 8
        for (int k = 0; k < 64; ++k) a2 = fmaf(flc[im8][k], fc2w[j * 64 + k], a2);
        fc2o[(size_t)img * 128 + j] = a2;
    }
}

// ---------------- fusion + softmax + 32-iter water-filling rebalance --------
__global__ __launch_bounds__(64) void k_final(const float* __restrict__ hlast,
                                              const float* __restrict__ fc2o,
                                              const float* __restrict__ gw,
                                              const float* __restrict__ gb,
                                              const float* __restrict__ fw,
                                              const float* __restrict__ fb,
                                              const float* __restrict__ finw,
                                              const float* __restrict__ finb,
                                              float* __restrict__ out)
{
    const int b = blockIdx.x, t = threadIdx.x;
    __shared__ float cf[128], nf[64], fu[64];
    #pragma unroll
    for (int jj = 0; jj < 2; ++jj) {
        const int j = t + jj * 64;
        float s = 0.f;
        for (int n = 0; n < NSTK; ++n) s += fc2o[(size_t)(b * NSTK + n) * 128 + j];
        cf[j] = s * (1.0f / 50.0f);
    }
    float s = 0.f;
    if (t < NSTK) {
        s = gb[t];
        for (int k = 0; k < HID; ++k) s = fmaf(hlast[b * HID + k], gw[t * HID + k], s);
    }
    nf[t] = (t < NSTK) ? s : 0.f;
    __syncthreads();
    float f = fb[t];
    for (int k = 0; k < NSTK; ++k) f = fmaf(nf[k], fw[t * 178 + k], f);
    for (int k = 0; k < 128; ++k) f = fmaf(cf[k], fw[t * 178 + 50 + k], f);
    fu[t] = fmaxf(f, 0.f);
    __syncthreads();
    float L = -3.4e38f;
    if (t < NSTK) {
        L = finb[t];
        for (int k = 0; k < 64; ++k) L = fmaf(fu[k], finw[t * 64 + k], L);
    }
    const float m = wave_max(L);
    const float e = (t < NSTK) ? expf(L - m) : 0.f;
    const float se = wave_sum(e);
    const float wv = e / se;
    float old = wv;
    float wc = fminf(fmaxf(wv, 0.f), 0.1f);
    for (int it = 0; it < 32; ++it) {
        const float leftover = wave_sum(old - wc);
        const bool mask = (wc != 0.1f);
        const float ssum = wave_sum(mask ? wc : 0.f);
        const float gift = (mask && ssum > 0.f) ? leftover * wc / ssum : 0.f;
        old = wc + gift;
        wc = fminf(fmaxf(old, 0.f), 0.1f);
    }
    if (t < NSTK) out[b * NSTK + t] = wc;
}

// ---------------------------------------------------------------------------
extern "C" void kernel_launch(void* const* d_in, const int* in_sizes, int n_in,
                              void* d_out, int out_size, void* d_ws, size_t ws_size,
                              hipStream_t stream)
{
    const float* x_num = (const float*)d_in[0];
    const float* x_img = (const float*)d_in[1];
    const float* c1w  = (const float*)d_in[2];
    const float* c1b  = (const float*)d_in[3];
    const float* c2w  = (const float*)d_in[4];
    const float* c2b  = (const float*)d_in[5];
    const float* fc1w = (const float*)d_in[6];
    const float* fc1b = (const float*)d_in[7];
    const float* fbw  = (const float*)d_in[8];
    const float* fbb  = (const float*)d_in[9];
    const float* fc2w = (const float*)d_in[10];
    const float* fc2b = (const float*)d_in[11];
    const float* wih  = (const float*)d_in[12];
    const float* whh  = (const float*)d_in[13];
    const float* bih  = (const float*)d_in[14];
    const float* bhh  = (const float*)d_in[15];
    const float* gw   = (const float*)d_in[16];
    const float* gb   = (const float*)d_in[17];
    const float* fw   = (const float*)d_in[18];
    const float* fb   = (const float*)d_in[19];
    const float* finw = (const float*)d_in[20];
    const float* finb = (const float*)d_in[21];
    float* out = (float*)d_out;
    float* ws  = (float*)d_ws;
    if (ws_size < (size_t)WS_FLOATS * 4) return;

    ushort_t* whhf  = (ushort_t*)(ws + OFF_WHHF);
    ushort_t* wprep = (ushort_t*)(ws + OFF_WPREP);
    ushort_t* wfc1  = (ushort_t*)(ws + OFF_WFC1);
    float* GI       = ws + OFF_GI;
    float* hlast    = ws + OFF_HLAST;
    ushort_t* pool2 = (ushort_t*)(ws + OFF_POOL2);
    float* fc2o     = ws + OFF_FC2O;
    float* part     = ws + OFF_PART;

    (void)hipFuncSetAttribute(reinterpret_cast<const void*>(k_mega),
                              hipFuncAttributeMaxDynamicSharedMemorySize, SMEM_BYTES);

    k_pre   <<<960 + 2736, 384, 0, stream>>>(x_num, wih, bih, whh, c2w, fc1w,
                                             GI, whhf, wprep, wfc1);
    k_mega  <<<NIMG + 1, 512, SMEM_BYTES, stream>>>(x_img, c1w, c1b, c2b, wprep,
                                                    GI, whhf, bhh, pool2, hlast);
    k_fc1   <<<50 * 16, 256, 0, stream>>>(pool2, wfc1, part);
    k_post  <<<100, 512, 0, stream>>>(part, fc1b, fbw, fbb, fc2w, fc2b, out, fc2o);
    k_final <<<NBATCH, 64, 0, stream>>>(hlast, fc2o, gw, gb, fw, fb, finw, finb, out);
}

// Round 8
// 148.705 us; speedup vs baseline: 1.9717x; 1.0344x over previous
//
#include <hip/hip_runtime.h>
#include <hip/hip_bf16.h>

typedef unsigned short ushort_t;
typedef short short8_t __attribute__((ext_vector_type(8)));
typedef float f32x4 __attribute__((ext_vector_type(4)));
typedef float f32x16 __attribute__((ext_vector_type(16)));
typedef ushort_t us4_t __attribute__((ext_vector_type(4)));

#define NBATCH 16
#define SEQ    60
#define NSTK   50
#define HID    128
#define G3     384
#define NIMG   800
#define IH     64
#define IW     60
#define P1H    32
#define P1W    30
#define P2C    64
#define FCIN   15360

// ---- workspace layout (float offsets) ----
#define OFF_WHHF   0u          // 49152 ushort  = 24576 f
#define OFF_WPREP  24576u      // 18432 ushort  = 9216 f
#define OFF_WFC1   33792u      // 983040 ushort = 491520 f
#define OFF_GI     525312u     // 368640 f
#define OFF_HLAST  893952u     // 2048 f
#define OFF_POOL2  896000u     // 800*15360 bf16 = 6144000 f
#define OFF_FC2O   7040000u    // 102400 f
#define OFF_PART   7142400u    // 16*800*64 = 819200 f
#define WS_FLOATS  7961600u    // ~31.8 MB

// swizzle element counts for k_pre
#define E_WHH  49152
#define E_WPR  18432
#define E_FC1  983040
#define E_TOT  (E_WHH + E_WPR + E_FC1)   // 1050624 = 2736*384

// ------------- shared-memory layouts (half-image CNN blocks) -------------
struct __align__(16) ConvS {
    ushort_t pool1t[18][4][32][8];     // 36864 B  [ly][cg][xs][ch8]; ly = 2*ypl+ro
    union {
        float    imgp[35][60];         //  8400 B  (conv1 phase; img rows base..base+34)
        ushort_t pool2s[64][120];      // 15360 B  (conv2 staging, 8 yp rows)
    } u;
};                                      // 52224 B  -> 3 blocks/CU
struct __align__(16) GruS {
    float    gh[16 * 388];             // 24832 B
    ushort_t hb[16 * 136];             //  4352 B
};                                      // 29184 B
#define SMEM_BYTES 52224

__device__ __forceinline__ float fast_sig(float x) {
    const float e = __expf(-x);
    return __builtin_amdgcn_rcpf(1.f + e);
}
__device__ __forceinline__ float fast_tanh(float x) {
    const float xc = fmaxf(fminf(x, 15.f), -15.f);
    const float e = __expf(2.f * xc);
    return (e - 1.f) * __builtin_amdgcn_rcpf(e + 1.f);
}

// ---------------- k_pre: GI (blocks 0..959) + weight swizzles (960..) ----------------
__global__ __launch_bounds__(384) void k_pre(const float* __restrict__ xnum,
                                             const float* __restrict__ wih,
                                             const float* __restrict__ bih,
                                             const float* __restrict__ whh,
                                             const float* __restrict__ c2w,
                                             const float* __restrict__ fc1w,
                                             float* __restrict__ GI,
                                             ushort_t* __restrict__ whhf,
                                             ushort_t* __restrict__ wprep,
                                             ushort_t* __restrict__ wfc1)
{
    const int bid = blockIdx.x;
    if (bid < 960) {
        const int s = bid >> 4, b = bid & 15;
        const int j = threadIdx.x;
        const float* xr = xnum + (size_t)(b * SEQ + s) * NSTK;   // block-uniform -> scalar loads
        const float* wr = wih + (size_t)j * NSTK;
        float a = bih[j];
        #pragma unroll 10
        for (int k = 0; k < NSTK; ++k) a = fmaf(xr[k], wr[k], a);
        GI[((size_t)s * 16 + b) * G3 + j] = a;
        return;
    }
    const int idx = (bid - 960) * 384 + threadIdx.x;
    if (idx < E_WHH) {
        const int e = idx;                  // (((jt*4+ks)*64 + l)*8 + i)
        const int i = e & 7, l = (e >> 3) & 63, ksj = e >> 9;
        const int ks = ksj & 3, jt = ksj >> 2;
        const int j = jt * 16 + (l & 15);
        const int k = ks * 32 + ((l >> 4) << 3) + i;
        __hip_bfloat16 hv = __float2bfloat16(whh[j * HID + k]);
        whhf[e] = *(ushort_t*)&hv;
    } else if (idx < E_WHH + E_WPR) {
        const int e = idx - E_WHH;          // (((m*9+tap)*2+ks)*64 + l)*8 + i
        const int i = e & 7, l = (e >> 3) & 63, rest = e >> 9;
        const int ks = rest & 1, mt = rest >> 1;
        const int tap = mt % 9, mm = mt / 9;
        const int oc = mm * 32 + (l & 31);
        const int ic = ks * 16 + ((l >> 5) << 3) + i;
        __hip_bfloat16 hv = __float2bfloat16(c2w[((size_t)oc * 32 + ic) * 9 + tap]);
        wprep[e] = *(ushort_t*)&hv;
    } else if (idx < E_TOT) {
        const int e = idx - (E_WHH + E_WPR); // ((T*4+n)*64 + l)*8 + i
        const int i = e & 7, l = (e >> 3) & 63, rest = e >> 9;
        const int n = rest & 3, T = rest >> 2;
        const int oc = n * 16 + (l & 15);
        const int k = T * 32 + ((l >> 4) << 3) + i;
        __hip_bfloat16 hv = __float2bfloat16(fc1w[(size_t)oc * FCIN + k]);
        wfc1[e] = *(ushort_t*)&hv;
    }
}

// ------- mega kernel: block 0 = GRU, blocks 1..1600 = one image HALF each -------
__global__ __launch_bounds__(512, 3) void k_mega(const float* __restrict__ x_img,
                                                 const float* __restrict__ c1w,
                                                 const float* __restrict__ c1b,
                                                 const float* __restrict__ c2b,
                                                 const ushort_t* __restrict__ wprep,
                                                 const float* __restrict__ GI,
                                                 const ushort_t* __restrict__ whhf,
                                                 const float* __restrict__ bhh,
                                                 ushort_t* __restrict__ pool2,
                                                 float* __restrict__ hlast)
{
    extern __shared__ char smraw[];
    const int tid = threadIdx.x;
    const int bid = blockIdx.x;

    if (bid == 0) {
        // =========== GRU: W_hh frags in regs, GI prefetch, h in regs ===========
        GruS* g = (GruS*)smraw;
        const int w = tid >> 6, l = tid & 63;
        const int arow = l & 15, kq = l >> 4;
        short8_t wfr[3][4];
        #pragma unroll
        for (int jj = 0; jj < 3; ++jj)
            #pragma unroll
            for (int ks = 0; ks < 4; ++ks)
                wfr[jj][ks] = *(const short8_t*)&whhf[((((w * 3 + jj) * 4 + ks) * 64 + l) * 8)];

        const int b = tid >> 5, hh0 = (tid & 31) * 4;
        const f32x4 bhr = *(const f32x4*)&bhh[hh0];
        const f32x4 bhz = *(const f32x4*)&bhh[128 + hh0];
        const f32x4 bhn = *(const f32x4*)&bhh[256 + hh0];
        float h0 = 0.f, h1 = 0.f, h2 = 0.f, h3 = 0.f;
        for (int i = tid; i < 1088; i += 512) ((unsigned int*)g->hb)[i] = 0u;
        const float* gi0 = GI + b * G3 + hh0;
        f32x4 cr = *(const f32x4*)(gi0);
        f32x4 cz = *(const f32x4*)(gi0 + 128);
        f32x4 cn = *(const f32x4*)(gi0 + 256);
        __syncthreads();

        for (int s = 0; s < SEQ; ++s) {
            const int sn = (s + 1 < SEQ) ? s + 1 : s;
            const float* gnx = GI + ((size_t)sn * 16 + b) * G3 + hh0;
            const f32x4 nr = *(const f32x4*)(gnx);
            const f32x4 nz = *(const f32x4*)(gnx + 128);
            const f32x4 nn = *(const f32x4*)(gnx + 256);

            #pragma unroll
            for (int jj = 0; jj < 3; ++jj) {
                f32x4 a = {0.f, 0.f, 0.f, 0.f};
                #pragma unroll
                for (int ks = 0; ks < 4; ++ks) {
                    short8_t af = *(const short8_t*)&g->hb[arow * 136 + ks * 32 + kq * 8];
                    a = __builtin_amdgcn_mfma_f32_16x16x32_bf16(af, wfr[jj][ks], a, 0, 0, 0);
                }
                const int jt = w * 3 + jj;
                #pragma unroll
                for (int r = 0; r < 4; ++r)
                    g->gh[(kq * 4 + r) * 388 + jt * 16 + arow] = a[r];
            }
            __syncthreads();

            const f32x4 gr = *(const f32x4*)&g->gh[b * 388 + hh0];
            const f32x4 gz = *(const f32x4*)&g->gh[b * 388 + 128 + hh0];
            const f32x4 gn = *(const f32x4*)&g->gh[b * 388 + 256 + hh0];
            float hv0, hv1, hv2, hv3;
            {
                const float r0 = fast_sig(cr[0] + gr[0] + bhr[0]);
                const float z0 = fast_sig(cz[0] + gz[0] + bhz[0]);
                const float n0 = fast_tanh(cn[0] + r0 * (gn[0] + bhn[0]));
                hv0 = (1.f - z0) * n0 + z0 * h0;
                const float r1 = fast_sig(cr[1] + gr[1] + bhr[1]);
                const float z1 = fast_sig(cz[1] + gz[1] + bhz[1]);
                const float n1 = fast_tanh(cn[1] + r1 * (gn[1] + bhn[1]));
                hv1 = (1.f - z1) * n1 + z1 * h1;
                const float r2 = fast_sig(cr[2] + gr[2] + bhr[2]);
                const float z2 = fast_sig(cz[2] + gz[2] + bhz[2]);
                const float n2 = fast_tanh(cn[2] + r2 * (gn[2] + bhn[2]));
                hv2 = (1.f - z2) * n2 + z2 * h2;
                const float r3 = fast_sig(cr[3] + gr[3] + bhr[3]);
                const float z3 = fast_sig(cz[3] + gz[3] + bhz[3]);
                const float n3 = fast_tanh(cn[3] + r3 * (gn[3] + bhn[3]));
                hv3 = (1.f - z3) * n3 + z3 * h3;
            }
            h0 = hv0; h1 = hv1; h2 = hv2; h3 = hv3;
            us4_t hp;
            { __hip_bfloat16 t0 = __float2bfloat16(h0); hp[0] = *(ushort_t*)&t0; }
            { __hip_bfloat16 t1 = __float2bfloat16(h1); hp[1] = *(ushort_t*)&t1; }
            { __hip_bfloat16 t2 = __float2bfloat16(h2); hp[2] = *(ushort_t*)&t2; }
            { __hip_bfloat16 t3 = __float2bfloat16(h3); hp[3] = *(ushort_t*)&t3; }
            *(us4_t*)&g->hb[b * 136 + hh0] = hp;
            cr = nr; cz = nz; cn = nn;
            __syncthreads();
        }
        f32x4 ho = {h0, h1, h2, h3};
        *(f32x4*)&hlast[b * HID + hh0] = ho;
        return;
    }

    // ================== CNN branch, one image HALF per block ==================
    ConvS* c = (ConvS*)smraw;
    const int img  = (bid - 1) >> 1;
    const int half = (bid - 1) & 1;
    const float* xim = x_img + (size_t)img * (IH * IW);
    const int rowbase = 29 * half;              // first image row in LDS

    // zero unwritten halo row (ly: half0->0, half1->17) + x halo cols 0,31
    {
        const short8_t z = {0, 0, 0, 0, 0, 0, 0, 0};
        const int zrow = half ? 17 : 0;
        if (tid < 128) {                        // zrow: 4 cg * 32 xs
            const int cg = tid >> 5, xs = tid & 31;
            *(short8_t*)&c->pool1t[zrow][cg][xs][0] = z;
        } else if (tid < 272) {                 // halo cols: 18 ly * 4 cg * 2
            const int q = tid - 128;
            const int ly = q / 8, cg = (q >> 1) & 3, xs = (q & 1) * 31;
            *(short8_t*)&c->pool1t[ly][cg][xs][0] = z;
        }
    }
    // copy 35 image rows to LDS (float4: 35*60/4 = 525 > 512 -> MUST stride!)
    {
        const f32x4* src = (const f32x4*)(xim + rowbase * IW);
        f32x4* dst = (f32x4*)c->u.imgp;
        for (int i = tid; i < 525; i += 512) dst[i] = src[i];
    }
    __syncthreads();

    // ---- conv1+relu+pool1: 17 pool rows x 30 px = 510 jobs, 1/thread ----
    if (tid < 510) {
        const int gj = tid / 30, px = tid - gj * 30;     // gj: local pool row 0..16
        const int g = half * 15 + gj;                    // global pool row
        const int ly = gj + 1 - half;                    // pool1t row
        float patch[4][4];
        #pragma unroll
        for (int yy = 0; yy < 4; ++yy) {
            const int giy = 2 * g - 1 + yy;              // global image row
            const int liy = giy - rowbase;
            #pragma unroll
            for (int xx = 0; xx < 4; ++xx) {
                const int ix = 2 * px - 1 + xx;
                patch[yy][xx] = (giy >= 0 && giy < IH && ix >= 0 && ix < IW)
                                    ? c->u.imgp[liy][ix] : 0.f;
            }
        }
        #pragma unroll
        for (int cg = 0; cg < 4; ++cg) {
            short8_t outv;
            #pragma unroll
            for (int ch8 = 0; ch8 < 8; ++ch8) {
                const int ch = cg * 8 + ch8;
                float wr[9];
                #pragma unroll
                for (int q = 0; q < 9; ++q) wr[q] = c1w[ch * 9 + q];   // uniform -> SGPR
                const float bia = c1b[ch];
                float best = 0.f;
                #pragma unroll
                for (int dy = 0; dy < 2; ++dy)
                    #pragma unroll
                    for (int dx = 0; dx < 2; ++dx) {
                        float sv = 0.f;
                        #pragma unroll
                        for (int ky = 0; ky < 3; ++ky)
                            #pragma unroll
                            for (int kx = 0; kx < 3; ++kx)
                                sv = fmaf(patch[dy + ky][dx + kx], wr[ky * 3 + kx], sv);
                        best = fmaxf(best, sv + bia);
                    }
                __hip_bfloat16 hv = __float2bfloat16(best);
                outv[ch8] = *(short*)&hv;
            }
            *(short8_t*)&c->pool1t[ly][cg][px + 1][0] = outv;
        }
    }
    __syncthreads();   // conv1 done; imgp dead -> pool2s reuse

    // ---- conv2 bf16 MFMA 32x32x16 implicit GEMM, 8 yp rows, staged flush ----
    {
        const int w  = tid >> 6, l = tid & 63;
        const int m  = w & 1;
        const int hi = l >> 5;
        const int col = l & 31;

        short8_t af[9][2];
        #pragma unroll
        for (int tap = 0; tap < 9; ++tap)
            #pragma unroll
            for (int ks = 0; ks < 2; ++ks)
                af[tap][ks] = *(const short8_t*)&wprep[(((m * 9 + tap) * 2 + ks) * 64 + l) * 8];
        float bia[16];
        #pragma unroll
        for (int r = 0; r < 16; ++r)
            bia[r] = c2b[m * 32 + (r & 3) + 8 * (r >> 2) + 4 * hi];

        const bool wr = ((col & 1) == 0) && (col < 30);
        const int px = col >> 1;

        #pragma unroll
        for (int yy = 0; yy < 2; ++yy) {
            const int ypl = (w >> 1) + yy * 4;           // 0..7 local pooled row
            f32x16 a0, a1;
            #pragma unroll
            for (int r = 0; r < 16; ++r) { a0[r] = 0.f; a1[r] = 0.f; }
            #pragma unroll
            for (int ro = 0; ro < 4; ++ro) {
                const int ly = 2 * ypl + ro;             // 0..17, halo rows pre-zeroed
                short8_t bf[3][2];
                #pragma unroll
                for (int kx = 0; kx < 3; ++kx)
                    #pragma unroll
                    for (int ks = 0; ks < 2; ++ks)
                        bf[kx][ks] = *(const short8_t*)&c->pool1t[ly][ks * 2 + hi][kx + col][0];
                if (ro < 3) {
                    #pragma unroll
                    for (int kx = 0; kx < 3; ++kx)
                        #pragma unroll
                        for (int ks = 0; ks < 2; ++ks)
                            a0 = __builtin_amdgcn_mfma_f32_32x32x16_bf16(af[ro * 3 + kx][ks], bf[kx][ks], a0, 0, 0, 0);
                }
                if (ro >= 1) {
                    #pragma unroll
                    for (int kx = 0; kx < 3; ++kx)
                        #pragma unroll
                        for (int ks = 0; ks < 2; ++ks)
                            a1 = __builtin_amdgcn_mfma_f32_32x32x16_bf16(af[(ro - 1) * 3 + kx][ks], bf[kx][ks], a1, 0, 0, 0);
                }
            }
            #pragma unroll
            for (int r = 0; r < 16; ++r) {
                float v = fmaxf(a0[r], a1[r]);
                v = fmaxf(v, __shfl_xor(v, 1, 64));
                v = fmaxf(v + bia[r], 0.f);
                if (wr) {
                    const int oc = m * 32 + (r & 3) + 8 * (r >> 2) + 4 * hi;
                    __hip_bfloat16 hv = __float2bfloat16(v);
                    c->u.pool2s[oc][ypl * 15 + px] = *(ushort_t*)&hv;
                }
            }
        }
        __syncthreads();   // staging complete
        // coalesced flush: 960 int4 = 64 oc x 15 int4 (this half's 120 ushorts/oc)
        {
            int4* dst = (int4*)(pool2 + (size_t)img * FCIN);
            const int4* src = (const int4*)c->u.pool2s;
            #pragma unroll
            for (int jj = 0; jj < 2; ++jj) {
                const int i = tid + jj * 512;
                if (i < 960) {
                    const int oc = i / 15, cc = i - oc * 15;
                    dst[oc * 30 + half * 15 + cc] = src[i];
                }
            }
        }
    }
}

// -------- fc1 split-K MFMA: 50 M-tiles x 16 K-splits, part[ks][img][oc] --------
__global__ __launch_bounds__(256) void k_fc1(const ushort_t* __restrict__ pool2,
                                             const ushort_t* __restrict__ wfc1,
                                             float* __restrict__ part)
{
    const int mt = blockIdx.x >> 4;             // 0..49 (16 images)
    const int ks = blockIdx.x & 15;             // K-split of 960
    const int n = threadIdx.x >> 6, l = threadIdx.x & 63;   // wave = oc tile
    const int arow = l & 15, kq = l >> 4;
    const int img16 = mt * 16;
    const ushort_t* Ab = pool2 + (size_t)(img16 + arow) * FCIN + ks * 960 + kq * 8;
    const ushort_t* Bb = wfc1 + ((size_t)(ks * 30 * 4 + n) * 64 + l) * 8;
    f32x4 acc0 = {0.f, 0.f, 0.f, 0.f}, acc1 = {0.f, 0.f, 0.f, 0.f};
    #pragma unroll 5
    for (int t = 0; t < 30; t += 2) {
        const short8_t aA = *(const short8_t*)(Ab + (size_t)t * 32);
        const short8_t bA = *(const short8_t*)(Bb + (size_t)t * 2048);
        const short8_t aB = *(const short8_t*)(Ab + (size_t)(t + 1) * 32);
        const short8_t bB = *(const short8_t*)(Bb + (size_t)(t + 1) * 2048);
        acc0 = __builtin_amdgcn_mfma_f32_16x16x32_bf16(aA, bA, acc0, 0, 0, 0);
        acc1 = __builtin_amdgcn_mfma_f32_16x16x32_bf16(aB, bB, acc1, 0, 0, 0);
    }
    float* dst = &part[((size_t)ks * NIMG + img16 + kq * 4) * 64 + n * 16 + arow];
    #pragma unroll
    for (int r = 0; r < 4; ++r)
        dst[(size_t)r * 64] = acc0[r] + acc1[r];
}

__device__ __forceinline__ float wave_sum(float v) {
    #pragma unroll
    for (int o = 32; o > 0; o >>= 1) v += __shfl_xor(v, o, 64);
    return v;
}
__device__ __forceinline__ float wave_max(float v) {
    #pragma unroll
    for (int o = 32; o > 0; o >>= 1) v = fmaxf(v, __shfl_xor(v, o, 64));
    return v;
}

// -------- reduce fc1 partials + relu + binary head + fc2 (8 imgs/block) --------
__global__ __launch_bounds__(512) void k_post(const float* __restrict__ part,
                                              const float* __restrict__ fc1b,
                                              const float* __restrict__ fbw,
                                              const float* __restrict__ fbb,
                                              const float* __restrict__ fc2w,
                                              const float* __restrict__ fc2b,
                                              float* __restrict__ out,
                                              float* __restrict__ fc2o)
{
    const int t = threadIdx.x;
    const int im8 = t >> 6;                     // 0..7 == wave id
    const int tl = t & 63;                      // oc
    const int img = blockIdx.x * 8 + im8;
    float s = fc1b[tl];
    #pragma unroll
    for (int ks = 0; ks < 16; ++ks) s += part[((size_t)ks * NIMG + img) * 64 + tl];
    const float f = fmaxf(s, 0.f);
    __shared__ float flc[8][64];
    flc[im8][tl] = f;
    const float bs = wave_sum(f * fbw[tl]);
    if (tl == 0) out[800 + img] = 1.f / (1.f + expf(-(bs + fbb[0])));
    __syncthreads();
    #pragma unroll
    for (int q = 0; q < 2; ++q) {
        const int j = tl + q * 64;
        float a2 = fc2b[j];
        #pragma unroll 8
        for (int k = 0; k < 64; ++k) a2 = fmaf(flc[im8][k], fc2w[j * 64 + k], a2);
        fc2o[(size_t)img * 128 + j] = a2;
    }
}

// ---------------- fusion + softmax + 32-iter water-filling rebalance --------
__global__ __launch_bounds__(64) void k_final(const float* __restrict__ hlast,
                                              const float* __restrict__ fc2o,
                                              const float* __restrict__ gw,
                                              const float* __restrict__ gb,
                                              const float* __restrict__ fw,
                                              const float* __restrict__ fb,
                                              const float* __restrict__ finw,
                                              const float* __restrict__ finb,
                                              float* __restrict__ out)
{
    const int b = blockIdx.x, t = threadIdx.x;
    __shared__ float cf[128], nf[64], fu[64];
    #pragma unroll
    for (int jj = 0; jj < 2; ++jj) {
        const int j = t + jj * 64;
        float s = 0.f;
        for (int n = 0; n < NSTK; ++n) s += fc2o[(size_t)(b * NSTK + n) * 128 + j];
        cf[j] = s * (1.0f / 50.0f);
    }
    float s = 0.f;
    if (t < NSTK) {
        s = gb[t];
        for (int k = 0; k < HID; ++k) s = fmaf(hlast[b * HID + k], gw[t * HID + k], s);
    }
    nf[t] = (t < NSTK) ? s : 0.f;
    __syncthreads();
    float f = fb[t];
    for (int k = 0; k < NSTK; ++k) f = fmaf(nf[k], fw[t * 178 + k], f);
    for (int k = 0; k < 128; ++k) f = fmaf(cf[k], fw[t * 178 + 50 + k], f);
    fu[t] = fmaxf(f, 0.f);
    __syncthreads();
    float L = -3.4e38f;
    if (t < NSTK) {
        L = finb[t];
        for (int k = 0; k < 64; ++k) L = fmaf(fu[k], finw[t * 64 + k], L);
    }
    const float m = wave_max(L);
    const float e = (t < NSTK) ? expf(L - m) : 0.f;
    const float se = wave_sum(e);
    const float wv = e / se;
    float old = wv;
    float wc = fminf(fmaxf(wv, 0.f), 0.1f);
    for (int it = 0; it < 32; ++it) {
        const float leftover = wave_sum(old - wc);
        const bool mask = (wc != 0.1f);
        const float ssum = wave_sum(mask ? wc : 0.f);
        const float gift = (mask && ssum > 0.f) ? leftover * wc / ssum : 0.f;
        old = wc + gift;
        wc = fminf(fmaxf(old, 0.f), 0.1f);
    }
    if (t < NSTK) out[b * NSTK + t] = wc;
}

// ---------------------------------------------------------------------------
extern "C" void kernel_launch(void* const* d_in, const int* in_sizes, int n_in,
                              void* d_out, int out_size, void* d_ws, size_t ws_size,
                              hipStream_t stream)
{
    const float* x_num = (const float*)d_in[0];
    const float* x_img = (const float*)d_in[1];
    const float* c1w  = (const float*)d_in[2];
    const float* c1b  = (const float*)d_in[3];
    const float* c2w  = (const float*)d_in[4];
    const float* c2b  = (const float*)d_in[5];
    const float* fc1w = (const float*)d_in[6];
    const float* fc1b = (const float*)d_in[7];
    const float* fbw  = (const float*)d_in[8];
    const float* fbb  = (const float*)d_in[9];
    const float* fc2w = (const float*)d_in[10];
    const float* fc2b = (const float*)d_in[11];
    const float* wih  = (const float*)d_in[12];
    const float* whh  = (const float*)d_in[13];
    const float* bih  = (const float*)d_in[14];
    const float* bhh  = (const float*)d_in[15];
    const float* gw   = (const float*)d_in[16];
    const float* gb   = (const float*)d_in[17];
    const float* fw   = (const float*)d_in[18];
    const float* fb   = (const float*)d_in[19];
    const float* finw = (const float*)d_in[20];
    const float* finb = (const float*)d_in[21];
    float* out = (float*)d_out;
    float* ws  = (float*)d_ws;
    if (ws_size < (size_t)WS_FLOATS * 4) return;

    ushort_t* whhf  = (ushort_t*)(ws + OFF_WHHF);
    ushort_t* wprep = (ushort_t*)(ws + OFF_WPREP);
    ushort_t* wfc1  = (ushort_t*)(ws + OFF_WFC1);
    float* GI       = ws + OFF_GI;
    float* hlast    = ws + OFF_HLAST;
    ushort_t* pool2 = (ushort_t*)(ws + OFF_POOL2);
    float* fc2o     = ws + OFF_FC2O;
    float* part     = ws + OFF_PART;

    (void)hipFuncSetAttribute(reinterpret_cast<const void*>(k_mega),
                              hipFuncAttributeMaxDynamicSharedMemorySize, SMEM_BYTES);

    k_pre   <<<960 + 2736, 384, 0, stream>>>(x_num, wih, bih, whh, c2w, fc1w,
                                             GI, whhf, wprep, wfc1);
    k_mega  <<<2 * NIMG + 1, 512, SMEM_BYTES, stream>>>(x_img, c1w, c1b, c2b, wprep,
                                                        GI, whhf, bhh, pool2, hlast);
    k_fc1   <<<50 * 16, 256, 0, stream>>>(pool2, wfc1, part);
    k_post  <<<100, 512, 0, stream>>>(part, fc1b, fbw, fbb, fc2w, fc2b, out, fc2o);
    k_final <<<NBATCH, 64, 0, stream>>>(hlast, fc2o, gw, gb, fw, fb, finw, finb, out);
}

// Round 10
// 146.134 us; speedup vs baseline: 2.0064x; 1.0176x over previous
//
#include <hip/hip_runtime.h>
#include <hip/hip_bf16.h>
#include <hip/hip_fp16.h>

typedef unsigned short ushort_t;
typedef short short8_t __attribute__((ext_vector_type(8)));
typedef _Float16 half8_t __attribute__((ext_vector_type(8)));
typedef _Float16 h2 __attribute__((ext_vector_type(2)));
typedef float f32x4 __attribute__((ext_vector_type(4)));
typedef float f32x16 __attribute__((ext_vector_type(16)));
typedef ushort_t us4_t __attribute__((ext_vector_type(4)));

#define NBATCH 16
#define SEQ    60
#define NSTK   50
#define HID    128
#define G3     384
#define NIMG   800
#define IH     64
#define IW     60
#define P1H    32
#define P1W    30
#define P2C    64
#define FCIN   15360

// ---- workspace layout (float offsets) ----
#define OFF_WHHF   0u          // 49152 ushort  = 24576 f   (GRU W_hh bf16 frags)
#define OFF_WPREP  24576u      // 18432 ushort  = 9216 f    (conv2 W f16 A-frags)
#define OFF_WFC1   33792u      // 983040 ushort = 491520 f  (fc1 W bf16 frags)
#define OFF_GI     525312u     // 368640 f
#define OFF_HLAST  893952u     // 2048 f
#define OFF_POOL2  896000u     // 800*15360 bf16 = 6144000 f
#define OFF_FC2O   7040000u    // 102400 f
#define OFF_PART   7142400u    // 16*800*64 = 819200 f
#define OFF_W1H    7961600u    // 160 uint (144 w1 half2 pairs + 16 c1b half2)
#define WS_FLOATS  7961760u    // ~31.8 MB

// swizzle element counts for k_pre
#define E_WHH  49152
#define E_WPR  18432
#define E_FC1  983040
#define E_W1H  160
#define E_TOT  (E_WHH + E_WPR + E_FC1 + E_W1H)   // 1050784 -> 2737 blocks of 384

// ------------- shared-memory layouts (half-image CNN blocks) -------------
struct __align__(16) ConvS {
    ushort_t pool1t[18][4][32][8];     // 36864 B  f16 bits, [ly][cg][xs][ch8]
    union {
        float    imgp[35][60];         //  8400 B  (conv1 phase)
        ushort_t pool2s[64][120];      // 15360 B  (conv2 staging, bf16)
    } u;
};                                      // 52224 B  -> 3 blocks/CU
struct __align__(16) GruS {
    float    gh[16 * 388];             // 24832 B
    ushort_t hb[16 * 136];             //  4352 B
};                                      // 29184 B
#define SMEM_BYTES 52224

__device__ __forceinline__ float fast_sig(float x) {
    const float e = __expf(-x);
    return __builtin_amdgcn_rcpf(1.f + e);
}
__device__ __forceinline__ float fast_tanh(float x) {
    const float xc = fmaxf(fminf(x, 15.f), -15.f);
    const float e = __expf(2.f * xc);
    return (e - 1.f) * __builtin_amdgcn_rcpf(e + 1.f);
}
__device__ __forceinline__ h2 hmax2v(h2 a, h2 b) {      // lowers to v_pk_max_f16
    h2 r;
    r[0] = a[0] > b[0] ? a[0] : b[0];
    r[1] = a[1] > b[1] ? a[1] : b[1];
    return r;
}

// ---------------- k_pre: GI (blocks 0..959) + weight swizzles (960..) ----------------
__global__ __launch_bounds__(384) void k_pre(const float* __restrict__ xnum,
                                             const float* __restrict__ wih,
                                             const float* __restrict__ bih,
                                             const float* __restrict__ whh,
                                             const float* __restrict__ c2w,
                                             const float* __restrict__ fc1w,
                                             const float* __restrict__ c1w,
                                             const float* __restrict__ c1b,
                                             float* __restrict__ GI,
                                             ushort_t* __restrict__ whhf,
                                             ushort_t* __restrict__ wprep,
                                             ushort_t* __restrict__ wfc1,
                                             unsigned int* __restrict__ w1h)
{
    const int bid = blockIdx.x;
    if (bid < 960) {
        const int s = bid >> 4, b = bid & 15;
        const int j = threadIdx.x;
        const float* xr = xnum + (size_t)(b * SEQ + s) * NSTK;   // block-uniform -> scalar loads
        const float* wr = wih + (size_t)j * NSTK;
        float a = bih[j];
        #pragma unroll 10
        for (int k = 0; k < NSTK; ++k) a = fmaf(xr[k], wr[k], a);
        GI[((size_t)s * 16 + b) * G3 + j] = a;
        return;
    }
    const int idx = (bid - 960) * 384 + threadIdx.x;
    if (idx < E_WHH) {
        const int e = idx;                  // (((jt*4+ks)*64 + l)*8 + i)  bf16 (GRU)
        const int i = e & 7, l = (e >> 3) & 63, ksj = e >> 9;
        const int ks = ksj & 3, jt = ksj >> 2;
        const int j = jt * 16 + (l & 15);
        const int k = ks * 32 + ((l >> 4) << 3) + i;
        __hip_bfloat16 hv = __float2bfloat16(whh[j * HID + k]);
        whhf[e] = *(ushort_t*)&hv;
    } else if (idx < E_WHH + E_WPR) {
        const int e = idx - E_WHH;          // conv2 A-frags, F16
        const int i = e & 7, l = (e >> 3) & 63, rest = e >> 9;
        const int ks = rest & 1, mt = rest >> 1;
        const int tap = mt % 9, mm = mt / 9;
        const int oc = mm * 32 + (l & 31);
        const int ic = ks * 16 + ((l >> 5) << 3) + i;
        const _Float16 hv = (_Float16)c2w[((size_t)oc * 32 + ic) * 9 + tap];
        wprep[e] = *(const ushort_t*)&hv;
    } else if (idx < E_WHH + E_WPR + E_FC1) {
        const int e = idx - (E_WHH + E_WPR); // fc1 B-frags bf16
        const int i = e & 7, l = (e >> 3) & 63, rest = e >> 9;
        const int n = rest & 3, T = rest >> 2;
        const int oc = n * 16 + (l & 15);
        const int k = T * 32 + ((l >> 4) << 3) + i;
        __hip_bfloat16 hv = __float2bfloat16(fc1w[(size_t)oc * FCIN + k]);
        wfc1[e] = *(ushort_t*)&hv;
    } else if (idx < E_TOT) {
        const int e = idx - (E_WHH + E_WPR + E_FC1);  // conv1 f16-pair weights + bias
        if (e < 144) {
            const int p = e / 9, tap = e - p * 9;     // pair p -> ch (p>>2)*8+(p&3)*2
            const int ch0 = (p >> 2) * 8 + (p & 3) * 2;
            const _Float16 lo = (_Float16)c1w[ch0 * 9 + tap];
            const _Float16 hi = (_Float16)c1w[(ch0 + 1) * 9 + tap];
            w1h[p * 9 + tap] = ((unsigned)*(const ushort_t*)&hi << 16) | *(const ushort_t*)&lo;
        } else {
            const int p = e - 144;
            const int ch0 = (p >> 2) * 8 + (p & 3) * 2;
            const _Float16 lo = (_Float16)c1b[ch0];
            const _Float16 hi = (_Float16)c1b[ch0 + 1];
            w1h[144 + p] = ((unsigned)*(const ushort_t*)&hi << 16) | *(const ushort_t*)&lo;
        }
    }
}

// ------- mega kernel: block 0 = GRU, blocks 1..1600 = one image HALF each -------
__global__ __launch_bounds__(512, 3) void k_mega(const float* __restrict__ x_img,
                                                 const unsigned int* __restrict__ w1h,
                                                 const float* __restrict__ c2b,
                                                 const ushort_t* __restrict__ wprep,
                                                 const float* __restrict__ GI,
                                                 const ushort_t* __restrict__ whhf,
                                                 const float* __restrict__ bhh,
                                                 ushort_t* __restrict__ pool2,
                                                 float* __restrict__ hlast)
{
    extern __shared__ char smraw[];
    const int tid = threadIdx.x;
    const int bid = blockIdx.x;

    if (bid == 0) {
        // =========== GRU: W_hh frags in regs, GI prefetch, h in regs ===========
        GruS* g = (GruS*)smraw;
        const int w = tid >> 6, l = tid & 63;
        const int arow = l & 15, kq = l >> 4;
        short8_t wfr[3][4];
        #pragma unroll
        for (int jj = 0; jj < 3; ++jj)
            #pragma unroll
            for (int ks = 0; ks < 4; ++ks)
                wfr[jj][ks] = *(const short8_t*)&whhf[((((w * 3 + jj) * 4 + ks) * 64 + l) * 8)];

        const int b = tid >> 5, hh0 = (tid & 31) * 4;
        const f32x4 bhr = *(const f32x4*)&bhh[hh0];
        const f32x4 bhz = *(const f32x4*)&bhh[128 + hh0];
        const f32x4 bhn = *(const f32x4*)&bhh[256 + hh0];
        float h0 = 0.f, h1 = 0.f, h2v = 0.f, h3 = 0.f;
        for (int i = tid; i < 1088; i += 512) ((unsigned int*)g->hb)[i] = 0u;
        const float* gi0 = GI + b * G3 + hh0;
        f32x4 cr = *(const f32x4*)(gi0);
        f32x4 cz = *(const f32x4*)(gi0 + 128);
        f32x4 cn = *(const f32x4*)(gi0 + 256);
        __syncthreads();

        for (int s = 0; s < SEQ; ++s) {
            const int sn = (s + 1 < SEQ) ? s + 1 : s;
            const float* gnx = GI + ((size_t)sn * 16 + b) * G3 + hh0;
            const f32x4 nr = *(const f32x4*)(gnx);
            const f32x4 nz = *(const f32x4*)(gnx + 128);
            const f32x4 nn = *(const f32x4*)(gnx + 256);

            #pragma unroll
            for (int jj = 0; jj < 3; ++jj) {
                f32x4 a = {0.f, 0.f, 0.f, 0.f};
                #pragma unroll
                for (int ks = 0; ks < 4; ++ks) {
                    short8_t af = *(const short8_t*)&g->hb[arow * 136 + ks * 32 + kq * 8];
                    a = __builtin_amdgcn_mfma_f32_16x16x32_bf16(af, wfr[jj][ks], a, 0, 0, 0);
                }
                const int jt = w * 3 + jj;
                #pragma unroll
                for (int r = 0; r < 4; ++r)
                    g->gh[(kq * 4 + r) * 388 + jt * 16 + arow] = a[r];
            }
            __syncthreads();

            const f32x4 gr = *(const f32x4*)&g->gh[b * 388 + hh0];
            const f32x4 gz = *(const f32x4*)&g->gh[b * 388 + 128 + hh0];
            const f32x4 gn = *(const f32x4*)&g->gh[b * 388 + 256 + hh0];
            float hv0, hv1, hv2, hv3;
            {
                const float r0 = fast_sig(cr[0] + gr[0] + bhr[0]);
                const float z0 = fast_sig(cz[0] + gz[0] + bhz[0]);
                const float n0 = fast_tanh(cn[0] + r0 * (gn[0] + bhn[0]));
                hv0 = (1.f - z0) * n0 + z0 * h0;
                const float r1 = fast_sig(cr[1] + gr[1] + bhr[1]);
                const float z1 = fast_sig(cz[1] + gz[1] + bhz[1]);
                const float n1 = fast_tanh(cn[1] + r1 * (gn[1] + bhn[1]));
                hv1 = (1.f - z1) * n1 + z1 * h1;
                const float r2 = fast_sig(cr[2] + gr[2] + bhr[2]);
                const float z2 = fast_sig(cz[2] + gz[2] + bhz[2]);
                const float n2 = fast_tanh(cn[2] + r2 * (gn[2] + bhn[2]));
                hv2 = (1.f - z2) * n2 + z2 * h2v;
                const float r3 = fast_sig(cr[3] + gr[3] + bhr[3]);
                const float z3 = fast_sig(cz[3] + gz[3] + bhz[3]);
                const float n3 = fast_tanh(cn[3] + r3 * (gn[3] + bhn[3]));
                hv3 = (1.f - z3) * n3 + z3 * h3;
            }
            h0 = hv0; h1 = hv1; h2v = hv2; h3 = hv3;
            us4_t hp;
            { __hip_bfloat16 t0 = __float2bfloat16(h0);  hp[0] = *(ushort_t*)&t0; }
            { __hip_bfloat16 t1 = __float2bfloat16(h1);  hp[1] = *(ushort_t*)&t1; }
            { __hip_bfloat16 t2 = __float2bfloat16(h2v); hp[2] = *(ushort_t*)&t2; }
            { __hip_bfloat16 t3 = __float2bfloat16(h3);  hp[3] = *(ushort_t*)&t3; }
            *(us4_t*)&g->hb[b * 136 + hh0] = hp;
            cr = nr; cz = nz; cn = nn;
            __syncthreads();
        }
        f32x4 ho = {h0, h1, h2v, h3};
        *(f32x4*)&hlast[b * HID + hh0] = ho;
        return;
    }

    // ================== CNN branch, one image HALF per block ==================
    ConvS* c = (ConvS*)smraw;
    const int img  = (bid - 1) >> 1;
    const int half = (bid - 1) & 1;
    const float* xim = x_img + (size_t)img * (IH * IW);
    const int rowbase = 29 * half;              // first image row in LDS

    // zero unwritten halo row (ly: half0->0, half1->17) + x halo cols 0,31
    {
        const short8_t z = {0, 0, 0, 0, 0, 0, 0, 0};
        const int zrow = half ? 17 : 0;
        if (tid < 128) {
            const int cg = tid >> 5, xs = tid & 31;
            *(short8_t*)&c->pool1t[zrow][cg][xs][0] = z;
        } else if (tid < 272) {
            const int q = tid - 128;
            const int ly = q / 8, cg = (q >> 1) & 3, xs = (q & 1) * 31;
            *(short8_t*)&c->pool1t[ly][cg][xs][0] = z;
        }
    }
    // copy 35 image rows to LDS (float4: 525 > 512 -> strided loop)
    {
        const f32x4* src = (const f32x4*)(xim + rowbase * IW);
        f32x4* dst = (f32x4*)c->u.imgp;
        for (int i = tid; i < 525; i += 512) dst[i] = src[i];
    }
    __syncthreads();

    // ---- conv1+relu+pool1 (packed f16): 17 pool rows x 30 px = 510 jobs ----
    if (tid < 510) {
        const int gj = tid / 30, px = tid - gj * 30;
        const int g = half * 15 + gj;
        const int ly = gj + 1 - half;
        const h2 z2 = {(_Float16)0.f, (_Float16)0.f};
        h2 patch2[4][4];
        #pragma unroll
        for (int yy = 0; yy < 4; ++yy) {
            const int giy = 2 * g - 1 + yy;
            const int liy = giy - rowbase;
            #pragma unroll
            for (int xx = 0; xx < 4; ++xx) {
                const int ix = 2 * px - 1 + xx;
                const float v = (giy >= 0 && giy < IH && ix >= 0 && ix < IW)
                                    ? c->u.imgp[liy][ix] : 0.f;
                const _Float16 vh = (_Float16)v;
                h2 p2; p2[0] = vh; p2[1] = vh;
                patch2[yy][xx] = p2;
            }
        }
        #pragma unroll
        for (int cg = 0; cg < 4; ++cg) {
            unsigned int ov[4];
            #pragma unroll
            for (int pr = 0; pr < 4; ++pr) {
                const int p = cg * 4 + pr;
                h2 wv[9];
                #pragma unroll
                for (int t = 0; t < 9; ++t) {          // uniform -> scalar loads
                    const unsigned int wu = w1h[p * 9 + t];
                    wv[t] = *(const h2*)&wu;
                }
                h2 a00 = z2, a01 = z2, a10 = z2, a11 = z2;
                #pragma unroll
                for (int ky = 0; ky < 3; ++ky)
                    #pragma unroll
                    for (int kx = 0; kx < 3; ++kx) {
                        const h2 wt = wv[ky * 3 + kx];
                        a00 = wt * patch2[ky][kx]     + a00;   // v_pk_fma_f16
                        a01 = wt * patch2[ky][kx + 1] + a01;
                        a10 = wt * patch2[ky + 1][kx] + a10;
                        a11 = wt * patch2[ky + 1][kx + 1] + a11;
                    }
                const unsigned int bu = w1h[144 + p];
                const h2 bia2 = *(const h2*)&bu;
                h2 m = hmax2v(hmax2v(a00, a01), hmax2v(a10, a11));
                h2 r = hmax2v(m + bia2, z2);
                ov[pr] = *(unsigned int*)&r;
            }
            *(uint4*)&c->pool1t[ly][cg][px + 1][0] = *(uint4*)ov;
        }
    }
    __syncthreads();   // conv1 done; imgp dead -> pool2s reuse

    // ---- conv2 f16 MFMA 32x32x16 implicit GEMM, staged flush ----
    {
        const int w  = tid >> 6, l = tid & 63;
        const int m  = w & 1;
        const int hi = l >> 5;
        const int col = l & 31;

        half8_t af[9][2];
        #pragma unroll
        for (int tap = 0; tap < 9; ++tap)
            #pragma unroll
            for (int ks = 0; ks < 2; ++ks)
                af[tap][ks] = *(const half8_t*)&wprep[(((m * 9 + tap) * 2 + ks) * 64 + l) * 8];
        float bia[16];
        #pragma unroll
        for (int r = 0; r < 16; ++r)
            bia[r] = c2b[m * 32 + (r & 3) + 8 * (r >> 2) + 4 * hi];

        const bool wr = ((col & 1) == 0) && (col < 30);
        const int px = col >> 1;

        #pragma unroll
        for (int yy = 0; yy < 2; ++yy) {
            const int ypl = (w >> 1) + yy * 4;           // 0..7 local pooled row
            f32x16 a0, a1;
            #pragma unroll
            for (int r = 0; r < 16; ++r) { a0[r] = 0.f; a1[r] = 0.f; }
            #pragma unroll
            for (int ro = 0; ro < 4; ++ro) {
                const int ly = 2 * ypl + ro;             // 0..17, halo rows pre-zeroed
                half8_t bf[3][2];
                #pragma unroll
                for (int kx = 0; kx < 3; ++kx)
                    #pragma unroll
                    for (int ks = 0; ks < 2; ++ks)
                        bf[kx][ks] = *(const half8_t*)&c->pool1t[ly][ks * 2 + hi][kx + col][0];
                if (ro < 3) {
                    #pragma unroll
                    for (int kx = 0; kx < 3; ++kx)
                        #pragma unroll
                        for (int ks = 0; ks < 2; ++ks)
                            a0 = __builtin_amdgcn_mfma_f32_32x32x16_f16(af[ro * 3 + kx][ks], bf[kx][ks], a0, 0, 0, 0);
                }
                if (ro >= 1) {
                    #pragma unroll
                    for (int kx = 0; kx < 3; ++kx)
                        #pragma unroll
                        for (int ks = 0; ks < 2; ++ks)
                            a1 = __builtin_amdgcn_mfma_f32_32x32x16_f16(af[(ro - 1) * 3 + kx][ks], bf[kx][ks], a1, 0, 0, 0);
                }
            }
            #pragma unroll
            for (int r = 0; r < 16; ++r) {
                float v = fmaxf(a0[r], a1[r]);
                v = fmaxf(v, __shfl_xor(v, 1, 64));
                v = fmaxf(v + bia[r], 0.f);
                if (wr) {
                    const int oc = m * 32 + (r & 3) + 8 * (r >> 2) + 4 * hi;
                    __hip_bfloat16 hv = __float2bfloat16(v);
                    c->u.pool2s[oc][ypl * 15 + px] = *(ushort_t*)&hv;
                }
            }
        }
        __syncthreads();   // staging complete
        // coalesced flush: 960 int4 = 64 oc x 15 int4 (this half's 120 ushorts/oc)
        {
            int4* dst = (int4*)(pool2 + (size_t)img * FCIN);
            const int4* src = (const int4*)c->u.pool2s;
            #pragma unroll
            for (int jj = 0; jj < 2; ++jj) {
                const int i = tid + jj * 512;
                if (i < 960) {
                    const int oc = i / 15, cc = i - oc * 15;
                    dst[oc * 30 + half * 15 + cc] = src[i];
                }
            }
        }
    }
}

// -------- fc1 split-K MFMA: 50 M-tiles x 16 K-splits, part[ks][img][oc] --------
__global__ __launch_bounds__(256) void k_fc1(const ushort_t* __restrict__ pool2,
                                             const ushort_t* __restrict__ wfc1,
                                             float* __restrict__ part)
{
    const int mt = blockIdx.x >> 4;             // 0..49 (16 images)
    const int ks = blockIdx.x & 15;             // K-split of 960
    const int n = threadIdx.x >> 6, l = threadIdx.x & 63;   // wave = oc tile
    const int arow = l & 15, kq = l >> 4;
    const int img16 = mt * 16;
    const ushort_t* Ab = pool2 + (size_t)(img16 + arow) * FCIN + ks * 960 + kq * 8;
    const ushort_t* Bb = wfc1 + ((size_t)(ks * 30 * 4 + n) * 64 + l) * 8;
    f32x4 acc0 = {0.f, 0.f, 0.f, 0.f}, acc1 = {0.f, 0.f, 0.f, 0.f};
    #pragma unroll 10
    for (int t = 0; t < 30; t += 2) {
        const short8_t aA = *(const short8_t*)(Ab + (size_t)t * 32);
        const short8_t bA = *(const short8_t*)(Bb + (size_t)t * 2048);
        const short8_t aB = *(const short8_t*)(Ab + (size_t)(t + 1) * 32);
        const short8_t bB = *(const short8_t*)(Bb + (size_t)(t + 1) * 2048);
        acc0 = __builtin_amdgcn_mfma_f32_16x16x32_bf16(aA, bA, acc0, 0, 0, 0);
        acc1 = __builtin_amdgcn_mfma_f32_16x16x32_bf16(aB, bB, acc1, 0, 0, 0);
    }
    float* dst = &part[((size_t)ks * NIMG + img16 + kq * 4) * 64 + n * 16 + arow];
    #pragma unroll
    for (int r = 0; r < 4; ++r)
        dst[(size_t)r * 64] = acc0[r] + acc1[r];
}

__device__ __forceinline__ float wave_sum(float v) {
    #pragma unroll
    for (int o = 32; o > 0; o >>= 1) v += __shfl_xor(v, o, 64);
    return v;
}
__device__ __forceinline__ float wave_max(float v) {
    #pragma unroll
    for (int o = 32; o > 0; o >>= 1) v = fmaxf(v, __shfl_xor(v, o, 64));
    return v;
}

// -------- reduce fc1 partials + relu + binary head + fc2 (8 imgs/block) --------
__global__ __launch_bounds__(512) void k_post(const float* __restrict__ part,
                                              const float* __restrict__ fc1b,
                                              const float* __restrict__ fbw,
                                              const float* __restrict__ fbb,
                                              const float* __restrict__ fc2w,
                                              const float* __restrict__ fc2b,
                                              float* __restrict__ out,
                                              float* __restrict__ fc2o)
{
    const int t = threadIdx.x;
    const int im8 = t >> 6;                     // 0..7 == wave id
    const int tl = t & 63;                      // oc
    const int img = blockIdx.x * 8 + im8;
    float s = fc1b[tl];
    #pragma unroll
    for (int ks = 0; ks < 16; ++ks) s += part[((size_t)ks * NIMG + img) * 64 + tl];
    const float f = fmaxf(s, 0.f);
    __shared__ float flc[8][64];
    flc[im8][tl] = f;
    const float bs = wave_sum(f * fbw[tl]);
    if (tl == 0) out[800 + img] = 1.f / (1.f + expf(-(bs + fbb[0])));
    __syncthreads();
    #pragma unroll
    for (int q = 0; q < 2; ++q) {
        const int j = tl + q * 64;
        float a2 = fc2b[j];
        #pragma unroll 8
        for (int k = 0; k < 64; ++k) a2 = fmaf(flc[im8][k], fc2w[j * 64 + k], a2);
        fc2o[(size_t)img * 128 + j] = a2;
    }
}

// ---------------- fusion + softmax + 32-iter water-filling rebalance --------
__global__ __launch_bounds__(64) void k_final(const float* __restrict__ hlast,
                                              const float* __restrict__ fc2o,
                                              const float* __restrict__ gw,
                                              const float* __restrict__ gb,
                                              const float* __restrict__ fw,
                                              const float* __restrict__ fb,
                                              const float* __restrict__ finw,
                                              const float* __restrict__ finb,
                                              float* __restrict__ out)
{
    const int b = blockIdx.x, t = threadIdx.x;
    __shared__ float cf[128], nf[64], fu[64];
    #pragma unroll
    for (int jj = 0; jj < 2; ++jj) {
        const int j = t + jj * 64;
        float s = 0.f;
        for (int n = 0; n < NSTK; ++n) s += fc2o[(size_t)(b * NSTK + n) * 128 + j];
        cf[j] = s * (1.0f / 50.0f);
    }
    float s = 0.f;
    if (t < NSTK) {
        s = gb[t];
        for (int k = 0; k < HID; ++k) s = fmaf(hlast[b * HID + k], gw[t * HID + k], s);
    }
    nf[t] = (t < NSTK) ? s : 0.f;
    __syncthreads();
    float f = fb[t];
    for (int k = 0; k < NSTK; ++k) f = fmaf(nf[k], fw[t * 178 + k], f);
    for (int k = 0; k < 128; ++k) f = fmaf(cf[k], fw[t * 178 + 50 + k], f);
    fu[t] = fmaxf(f, 0.f);
    __syncthreads();
    float L = -3.4e38f;
    if (t < NSTK) {
        L = finb[t];
        for (int k = 0; k < 64; ++k) L = fmaf(fu[k], finw[t * 64 + k], L);
    }
    const float m = wave_max(L);
    const float e = (t < NSTK) ? expf(L - m) : 0.f;
    const float se = wave_sum(e);
    const float wv = e / se;
    float old = wv;
    float wc = fminf(fmaxf(wv, 0.f), 0.1f);
    for (int it = 0; it < 32; ++it) {
        const float leftover = wave_sum(old - wc);
        const bool mask = (wc != 0.1f);
        const float ssum = wave_sum(mask ? wc : 0.f);
        const float gift = (mask && ssum > 0.f) ? leftover * wc / ssum : 0.f;
        old = wc + gift;
        wc = fminf(fmaxf(old, 0.f), 0.1f);
    }
    if (t < NSTK) out[b * NSTK + t] = wc;
}

// ---------------------------------------------------------------------------
extern "C" void kernel_launch(void* const* d_in, const int* in_sizes, int n_in,
                              void* d_out, int out_size, void* d_ws, size_t ws_size,
                              hipStream_t stream)
{
    const float* x_num = (const float*)d_in[0];
    const float* x_img = (const float*)d_in[1];
    const float* c1w  = (const float*)d_in[2];
    const float* c1b  = (const float*)d_in[3];
    const float* c2w  = (const float*)d_in[4];
    const float* c2b  = (const float*)d_in[5];
    const float* fc1w = (const float*)d_in[6];
    const float* fc1b = (const float*)d_in[7];
    const float* fbw  = (const float*)d_in[8];
    const float* fbb  = (const float*)d_in[9];
    const float* fc2w = (const float*)d_in[10];
    const float* fc2b = (const float*)d_in[11];
    const float* wih  = (const float*)d_in[12];
    const float* whh  = (const float*)d_in[13];
    const float* bih  = (const float*)d_in[14];
    const float* bhh  = (const float*)d_in[15];
    const float* gw   = (const float*)d_in[16];
    const float* gb   = (const float*)d_in[17];
    const float* fw   = (const float*)d_in[18];
    const float* fb   = (const float*)d_in[19];
    const float* finw = (const float*)d_in[20];
    const float* finb = (const float*)d_in[21];
    float* out = (float*)d_out;
    float* ws  = (float*)d_ws;
    if (ws_size < (size_t)WS_FLOATS * 4) return;

    ushort_t* whhf  = (ushort_t*)(ws + OFF_WHHF);
    ushort_t* wprep = (ushort_t*)(ws + OFF_WPREP);
    ushort_t* wfc1  = (ushort_t*)(ws + OFF_WFC1);
    float* GI       = ws + OFF_GI;
    float* hlast    = ws + OFF_HLAST;
    ushort_t* pool2 = (ushort_t*)(ws + OFF_POOL2);
    float* fc2o     = ws + OFF_FC2O;
    float* part     = ws + OFF_PART;
    unsigned int* w1h = (unsigned int*)(ws + OFF_W1H);

    (void)hipFuncSetAttribute(reinterpret_cast<const void*>(k_mega),
                              hipFuncAttributeMaxDynamicSharedMemorySize, SMEM_BYTES);

    k_pre   <<<960 + 2737, 384, 0, stream>>>(x_num, wih, bih, whh, c2w, fc1w, c1w, c1b,
                                             GI, whhf, wprep, wfc1, w1h);
    k_mega  <<<2 * NIMG + 1, 512, SMEM_BYTES, stream>>>(x_img, w1h, c2b, wprep,
                                                        GI, whhf, bhh, pool2, hlast);
    k_fc1   <<<50 * 16, 256, 0, stream>>>(pool2, wfc1, part);
    k_post  <<<100, 512, 0, stream>>>(part, fc1b, fbw, fbb, fc2w, fc2b, out, fc2o);
    k_final <<<NBATCH, 64, 0, stream>>>(hlast, fc2o, gw, gb, fw, fb, finw, finb, out);
}

// Round 11
// 138.432 us; speedup vs baseline: 2.1181x; 1.0556x over previous
//
#include <hip/hip_runtime.h>
#include <hip/hip_bf16.h>
#include <hip/hip_fp16.h>

typedef unsigned short ushort_t;
typedef short short8_t __attribute__((ext_vector_type(8)));
typedef _Float16 half8_t __attribute__((ext_vector_type(8)));
typedef _Float16 h2 __attribute__((ext_vector_type(2)));
typedef float f32x4 __attribute__((ext_vector_type(4)));
typedef float f32x16 __attribute__((ext_vector_type(16)));

#define NBATCH 16
#define SEQ    60
#define NSTK   50
#define HID    128
#define G3     384
#define NIMG   800
#define IH     64
#define IW     60
#define P1H    32
#define P1W    30
#define P2C    64
#define FCIN   15360

// ---- workspace layout (float offsets) ----
#define OFF_WHHF   0u          // 49152 ushort  = 24576 f   (GRU W_hh bf16 frags)
#define OFF_WPREP  24576u      // 18432 ushort  = 9216 f    (conv2 W f16 A-frags)
#define OFF_WFC1   33792u      // 983040 ushort = 491520 f  (fc1 W bf16 frags)
#define OFF_GI     525312u     // 368640 f
#define OFF_HLAST  893952u     // 2048 f
#define OFF_POOL2  896000u     // 800*15360 bf16 = 6144000 f
#define OFF_FC2O   7040000u    // 102400 f
#define OFF_PART   7142400u    // 16*800*64 = 819200 f
#define OFF_W1H    7961600u    // 160 uint (144 w1 half2 pairs + 16 c1b half2)
#define WS_FLOATS  7961760u    // ~31.8 MB

// swizzle element counts for k_pre
#define E_WHH  49152
#define E_WPR  18432
#define E_FC1  983040
#define E_W1H  160
#define E_TOT  (E_WHH + E_WPR + E_FC1 + E_W1H)   // 1050784 -> 2737 blocks of 384

// ------------- shared-memory layouts (half-image CNN blocks) -------------
struct __align__(16) ConvS {
    ushort_t pool1t[18][4][32][8];     // 36864 B  f16 bits, [ly][cg][xs][ch8]
    union {
        float    imgp[35][60];         //  8400 B  (conv1 phase)
        ushort_t pool2s[64][120];      // 15360 B  (conv2 staging, bf16)
    } u;
};                                      // 52224 B  -> 3 blocks/CU
struct __align__(16) GruS {
    ushort_t hb[2][16 * 136];          // 8704 B, double-buffered h (bf16)
};
#define SMEM_BYTES 52224

__device__ __forceinline__ float fast_sig(float x) {
    const float e = __expf(-x);
    return __builtin_amdgcn_rcpf(1.f + e);
}
__device__ __forceinline__ float fast_tanh(float x) {
    const float xc = fmaxf(fminf(x, 15.f), -15.f);
    const float e = __expf(2.f * xc);
    return (e - 1.f) * __builtin_amdgcn_rcpf(e + 1.f);
}
__device__ __forceinline__ h2 hmax2v(h2 a, h2 b) {      // lowers to v_pk_max_f16
    h2 r;
    r[0] = a[0] > b[0] ? a[0] : b[0];
    r[1] = a[1] > b[1] ? a[1] : b[1];
    return r;
}

// ---------------- k_pre: GI (blocks 0..959) + weight swizzles (960..) ----------------
__global__ __launch_bounds__(384) void k_pre(const float* __restrict__ xnum,
                                             const float* __restrict__ wih,
                                             const float* __restrict__ bih,
                                             const float* __restrict__ whh,
                                             const float* __restrict__ c2w,
                                             const float* __restrict__ fc1w,
                                             const float* __restrict__ c1w,
                                             const float* __restrict__ c1b,
                                             float* __restrict__ GI,
                                             ushort_t* __restrict__ whhf,
                                             ushort_t* __restrict__ wprep,
                                             ushort_t* __restrict__ wfc1,
                                             unsigned int* __restrict__ w1h)
{
    const int bid = blockIdx.x;
    if (bid < 960) {
        const int s = bid >> 4, b = bid & 15;
        const int j = threadIdx.x;
        const float* xr = xnum + (size_t)(b * SEQ + s) * NSTK;   // block-uniform -> scalar loads
        const float* wr = wih + (size_t)j * NSTK;
        float a = bih[j];
        #pragma unroll 10
        for (int k = 0; k < NSTK; ++k) a = fmaf(xr[k], wr[k], a);
        GI[((size_t)s * 16 + b) * G3 + j] = a;
        return;
    }
    const int idx = (bid - 960) * 384 + threadIdx.x;
    if (idx < E_WHH) {
        const int e = idx;                  // (((jt*4+ks)*64 + l)*8 + i)  bf16 (GRU)
        const int i = e & 7, l = (e >> 3) & 63, ksj = e >> 9;
        const int ks = ksj & 3, jt = ksj >> 2;
        const int j = jt * 16 + (l & 15);
        const int k = ks * 32 + ((l >> 4) << 3) + i;
        __hip_bfloat16 hv = __float2bfloat16(whh[j * HID + k]);
        whhf[e] = *(ushort_t*)&hv;
    } else if (idx < E_WHH + E_WPR) {
        const int e = idx - E_WHH;          // conv2 A-frags, F16
        const int i = e & 7, l = (e >> 3) & 63, rest = e >> 9;
        const int ks = rest & 1, mt = rest >> 1;
        const int tap = mt % 9, mm = mt / 9;
        const int oc = mm * 32 + (l & 31);
        const int ic = ks * 16 + ((l >> 5) << 3) + i;
        const _Float16 hv = (_Float16)c2w[((size_t)oc * 32 + ic) * 9 + tap];
        wprep[e] = *(const ushort_t*)&hv;
    } else if (idx < E_WHH + E_WPR + E_FC1) {
        const int e = idx - (E_WHH + E_WPR); // fc1 B-frags bf16
        const int i = e & 7, l = (e >> 3) & 63, rest = e >> 9;
        const int n = rest & 3, T = rest >> 2;
        const int oc = n * 16 + (l & 15);
        const int k = T * 32 + ((l >> 4) << 3) + i;
        __hip_bfloat16 hv = __float2bfloat16(fc1w[(size_t)oc * FCIN + k]);
        wfc1[e] = *(ushort_t*)&hv;
    } else if (idx < E_TOT) {
        const int e = idx - (E_WHH + E_WPR + E_FC1);  // conv1 f16-pair weights + bias
        if (e < 144) {
            const int p = e / 9, tap = e - p * 9;     // pair p -> ch (p>>2)*8+(p&3)*2
            const int ch0 = (p >> 2) * 8 + (p & 3) * 2;
            const _Float16 lo = (_Float16)c1w[ch0 * 9 + tap];
            const _Float16 hi = (_Float16)c1w[(ch0 + 1) * 9 + tap];
            w1h[p * 9 + tap] = ((unsigned)*(const ushort_t*)&hi << 16) | *(const ushort_t*)&lo;
        } else {
            const int p = e - 144;
            const int ch0 = (p >> 2) * 8 + (p & 3) * 2;
            const _Float16 lo = (_Float16)c1b[ch0];
            const _Float16 hi = (_Float16)c1b[ch0 + 1];
            w1h[144 + p] = ((unsigned)*(const ushort_t*)&hi << 16) | *(const ushort_t*)&lo;
        }
    }
}

// ------- mega kernel: block 0 = GRU, blocks 1..1600 = one image HALF each -------
__global__ __launch_bounds__(512, 2) void k_mega(const float* __restrict__ x_img,
                                                 const unsigned int* __restrict__ w1h,
                                                 const float* __restrict__ c2b,
                                                 const ushort_t* __restrict__ wprep,
                                                 const float* __restrict__ GI,
                                                 const ushort_t* __restrict__ whhf,
                                                 const float* __restrict__ bhh,
                                                 ushort_t* __restrict__ pool2,
                                                 float* __restrict__ hlast)
{
    extern __shared__ char smraw[];
    const int tid = threadIdx.x;
    const int bid = blockIdx.x;

    if (bid == 0) {
        // ===== GRU: one barrier/step, gates fully in-register =====
        // wave w owns hh slice [w*16, w*16+16): j-tiles {w, 8+w, 16+w} (gates r,z,n)
        GruS* g = (GruS*)smraw;
        const int w = tid >> 6, l = tid & 63;
        const int arow = l & 15, kq = l >> 4;          // A-frag: row=b index, k-chunk
        const int hh = w * 16 + (l & 15);              // D col -> hh
        const int b0 = (l >> 4) * 4;                   // D rows b0..b0+3
        short8_t wfr[3][4];
        #pragma unroll
        for (int g3 = 0; g3 < 3; ++g3)
            #pragma unroll
            for (int ks = 0; ks < 4; ++ks)
                wfr[g3][ks] = *(const short8_t*)&whhf[((((g3 * 8 + w) * 4 + ks) * 64 + l) * 8)];
        const float bhr = bhh[hh];
        const float bhz = bhh[128 + hh];
        const float bhn = bhh[256 + hh];
        float h[4] = {0.f, 0.f, 0.f, 0.f};
        for (int i = tid; i < 1088; i += 512) ((unsigned int*)g->hb[0])[i] = 0u;
        __syncthreads();

        int cur = 0;
        for (int s = 0; s < SEQ; ++s) {
            // per-lane GI loads for (b0+r, hh): 64B-coalesced within each 16-lane group
            const float* gis = GI + ((size_t)s * 16 + b0) * G3 + hh;
            float cr[4], cz[4], cn[4];
            #pragma unroll
            for (int r = 0; r < 4; ++r) {
                cr[r] = gis[r * G3];
                cz[r] = gis[r * G3 + 128];
                cn[r] = gis[r * G3 + 256];
            }
            // A-frags from hb[cur]; 3 gate accumulators in-register
            f32x4 ar = {0.f, 0.f, 0.f, 0.f};
            f32x4 az = {0.f, 0.f, 0.f, 0.f};
            f32x4 an = {0.f, 0.f, 0.f, 0.f};
            #pragma unroll
            for (int ks = 0; ks < 4; ++ks) {
                const short8_t af = *(const short8_t*)&g->hb[cur][arow * 136 + ks * 32 + kq * 8];
                ar = __builtin_amdgcn_mfma_f32_16x16x32_bf16(af, wfr[0][ks], ar, 0, 0, 0);
                az = __builtin_amdgcn_mfma_f32_16x16x32_bf16(af, wfr[1][ks], az, 0, 0, 0);
                an = __builtin_amdgcn_mfma_f32_16x16x32_bf16(af, wfr[2][ks], an, 0, 0, 0);
            }
            // gates in-register; lane holds (b0+r, hh) for r=0..3
            const int nxt = cur ^ 1;
            #pragma unroll
            for (int r = 0; r < 4; ++r) {
                const float rg = fast_sig(cr[r] + ar[r] + bhr);
                const float zg = fast_sig(cz[r] + az[r] + bhz);
                const float ng = fast_tanh(cn[r] + rg * (an[r] + bhn));
                h[r] = (1.f - zg) * ng + zg * h[r];
                __hip_bfloat16 t = __float2bfloat16(h[r]);
                g->hb[nxt][(b0 + r) * 136 + hh] = *(ushort_t*)&t;
            }
            __syncthreads();
            cur = nxt;
        }
        #pragma unroll
        for (int r = 0; r < 4; ++r) hlast[(b0 + r) * HID + hh] = h[r];
        return;
    }

    // ================== CNN branch, one image HALF per block ==================
    ConvS* c = (ConvS*)smraw;
    const int img  = (bid - 1) >> 1;
    const int half = (bid - 1) & 1;
    const float* xim = x_img + (size_t)img * (IH * IW);
    const int rowbase = 29 * half;              // first image row in LDS

    // zero unwritten halo row (ly: half0->0, half1->17) + x halo cols 0,31
    {
        const short8_t z = {0, 0, 0, 0, 0, 0, 0, 0};
        const int zrow = half ? 17 : 0;
        if (tid < 128) {
            const int cg = tid >> 5, xs = tid & 31;
            *(short8_t*)&c->pool1t[zrow][cg][xs][0] = z;
        } else if (tid < 272) {
            const int q = tid - 128;
            const int ly = q / 8, cg = (q >> 1) & 3, xs = (q & 1) * 31;
            *(short8_t*)&c->pool1t[ly][cg][xs][0] = z;
        }
    }
    // copy 35 image rows to LDS (float4: 525 > 512 -> strided loop)
    {
        const f32x4* src = (const f32x4*)(xim + rowbase * IW);
        f32x4* dst = (f32x4*)c->u.imgp;
        for (int i = tid; i < 525; i += 512) dst[i] = src[i];
    }
    __syncthreads();

    // ---- conv1+relu+pool1 (packed f16): 17 pool rows x 30 px = 510 jobs ----
    if (tid < 510) {
        const int gj = tid / 30, px = tid - gj * 30;
        const int g = half * 15 + gj;
        const int ly = gj + 1 - half;
        const h2 z2 = {(_Float16)0.f, (_Float16)0.f};
        h2 patch2[4][4];
        #pragma unroll
        for (int yy = 0; yy < 4; ++yy) {
            const int giy = 2 * g - 1 + yy;
            const int liy = giy - rowbase;
            #pragma unroll
            for (int xx = 0; xx < 4; ++xx) {
                const int ix = 2 * px - 1 + xx;
                const float v = (giy >= 0 && giy < IH && ix >= 0 && ix < IW)
                                    ? c->u.imgp[liy][ix] : 0.f;
                const _Float16 vh = (_Float16)v;
                h2 p2; p2[0] = vh; p2[1] = vh;
                patch2[yy][xx] = p2;
            }
        }
        #pragma unroll
        for (int cg = 0; cg < 4; ++cg) {
            unsigned int ov[4];
            #pragma unroll
            for (int pr = 0; pr < 4; ++pr) {
                const int p = cg * 4 + pr;
                h2 wv[9];
                #pragma unroll
                for (int t = 0; t < 9; ++t) {          // uniform -> scalar loads
                    const unsigned int wu = w1h[p * 9 + t];
                    wv[t] = *(const h2*)&wu;
                }
                h2 a00 = z2, a01 = z2, a10 = z2, a11 = z2;
                #pragma unroll
                for (int ky = 0; ky < 3; ++ky)
                    #pragma unroll
                    for (int kx = 0; kx < 3; ++kx) {
                        const h2 wt = wv[ky * 3 + kx];
                        a00 = wt * patch2[ky][kx]     + a00;   // v_pk_fma_f16
                        a01 = wt * patch2[ky][kx + 1] + a01;
                        a10 = wt * patch2[ky + 1][kx] + a10;
                        a11 = wt * patch2[ky + 1][kx + 1] + a11;
                    }
                const unsigned int bu = w1h[144 + p];
                const h2 bia2 = *(const h2*)&bu;
                h2 m = hmax2v(hmax2v(a00, a01), hmax2v(a10, a11));
                h2 r = hmax2v(m + bia2, z2);
                ov[pr] = *(unsigned int*)&r;
            }
            *(uint4*)&c->pool1t[ly][cg][px + 1][0] = *(uint4*)ov;
        }
    }
    __syncthreads();   // conv1 done; imgp dead -> pool2s reuse

    // ---- conv2 f16 MFMA 32x32x16 implicit GEMM, staged flush ----
    {
        const int w  = tid >> 6, l = tid & 63;
        const int m  = w & 1;
        const int hi = l >> 5;
        const int col = l & 31;

        half8_t af[9][2];
        #pragma unroll
        for (int tap = 0; tap < 9; ++tap)
            #pragma unroll
            for (int ks = 0; ks < 2; ++ks)
                af[tap][ks] = *(const half8_t*)&wprep[(((m * 9 + tap) * 2 + ks) * 64 + l) * 8];
        float bia[16];
        #pragma unroll
        for (int r = 0; r < 16; ++r)
            bia[r] = c2b[m * 32 + (r & 3) + 8 * (r >> 2) + 4 * hi];

        const bool wr = ((col & 1) == 0) && (col < 30);
        const int px = col >> 1;

        #pragma unroll
        for (int yy = 0; yy < 2; ++yy) {
            const int ypl = (w >> 1) + yy * 4;           // 0..7 local pooled row
            f32x16 a0, a1;
            #pragma unroll
            for (int r = 0; r < 16; ++r) { a0[r] = 0.f; a1[r] = 0.f; }
            #pragma unroll
            for (int ro = 0; ro < 4; ++ro) {
                const int ly = 2 * ypl + ro;             // 0..17, halo rows pre-zeroed
                half8_t bf[3][2];
                #pragma unroll
                for (int kx = 0; kx < 3; ++kx)
                    #pragma unroll
                    for (int ks = 0; ks < 2; ++ks)
                        bf[kx][ks] = *(const half8_t*)&c->pool1t[ly][ks * 2 + hi][kx + col][0];
                if (ro < 3) {
                    #pragma unroll
                    for (int kx = 0; kx < 3; ++kx)
                        #pragma unroll
                        for (int ks = 0; ks < 2; ++ks)
                            a0 = __builtin_amdgcn_mfma_f32_32x32x16_f16(af[ro * 3 + kx][ks], bf[kx][ks], a0, 0, 0, 0);
                }
                if (ro >= 1) {
                    #pragma unroll
                    for (int kx = 0; kx < 3; ++kx)
                        #pragma unroll
                        for (int ks = 0; ks < 2; ++ks)
                            a1 = __builtin_amdgcn_mfma_f32_32x32x16_f16(af[(ro - 1) * 3 + kx][ks], bf[kx][ks], a1, 0, 0, 0);
                }
            }
            #pragma unroll
            for (int r = 0; r < 16; ++r) {
                float v = fmaxf(a0[r], a1[r]);
                v = fmaxf(v, __shfl_xor(v, 1, 64));
                v = fmaxf(v + bia[r], 0.f);
                if (wr) {
                    const int oc = m * 32 + (r & 3) + 8 * (r >> 2) + 4 * hi;
                    __hip_bfloat16 hv = __float2bfloat16(v);
                    c->u.pool2s[oc][ypl * 15 + px] = *(ushort_t*)&hv;
                }
            }
        }
        __syncthreads();   // staging complete
        // coalesced flush: 960 int4 = 64 oc x 15 int4 (this half's 120 ushorts/oc)
        {
            int4* dst = (int4*)(pool2 + (size_t)img * FCIN);
            const int4* src = (const int4*)c->u.pool2s;
            #pragma unroll
            for (int jj = 0; jj < 2; ++jj) {
                const int i = tid + jj * 512;
                if (i < 960) {
                    const int oc = i / 15, cc = i - oc * 15;
                    dst[oc * 30 + half * 15 + cc] = src[i];
                }
            }
        }
    }
}

// -------- fc1 split-K MFMA: 50 M-tiles x 16 K-splits, part[ks][img][oc] --------
__global__ __launch_bounds__(256) void k_fc1(const ushort_t* __restrict__ pool2,
                                             const ushort_t* __restrict__ wfc1,
                                             float* __restrict__ part)
{
    const int mt = blockIdx.x >> 4;             // 0..49 (16 images)
    const int ks = blockIdx.x & 15;             // K-split of 960
    const int n = threadIdx.x >> 6, l = threadIdx.x & 63;   // wave = oc tile
    const int arow = l & 15, kq = l >> 4;
    const int img16 = mt * 16;
    const ushort_t* Ab = pool2 + (size_t)(img16 + arow) * FCIN + ks * 960 + kq * 8;
    const ushort_t* Bb = wfc1 + ((size_t)(ks * 30 * 4 + n) * 64 + l) * 8;
    f32x4 acc0 = {0.f, 0.f, 0.f, 0.f}, acc1 = {0.f, 0.f, 0.f, 0.f};
    #pragma unroll 10
    for (int t = 0; t < 30; t += 2) {
        const short8_t aA = *(const short8_t*)(Ab + (size_t)t * 32);
        const short8_t bA = *(const short8_t*)(Bb + (size_t)t * 2048);
        const short8_t aB = *(const short8_t*)(Ab + (size_t)(t + 1) * 32);
        const short8_t bB = *(const short8_t*)(Bb + (size_t)(t + 1) * 2048);
        acc0 = __builtin_amdgcn_mfma_f32_16x16x32_bf16(aA, bA, acc0, 0, 0, 0);
        acc1 = __builtin_amdgcn_mfma_f32_16x16x32_bf16(aB, bB, acc1, 0, 0, 0);
    }
    float* dst = &part[((size_t)ks * NIMG + img16 + kq * 4) * 64 + n * 16 + arow];
    #pragma unroll
    for (int r = 0; r < 4; ++r)
        dst[(size_t)r * 64] = acc0[r] + acc1[r];
}

__device__ __forceinline__ float wave_sum(float v) {
    #pragma unroll
    for (int o = 32; o > 0; o >>= 1) v += __shfl_xor(v, o, 64);
    return v;
}
__device__ __forceinline__ float wave_max(float v) {
    #pragma unroll
    for (int o = 32; o > 0; o >>= 1) v = fmaxf(v, __shfl_xor(v, o, 64));
    return v;
}

// -------- reduce fc1 partials + relu + binary head + fc2 (8 imgs/block) --------
__global__ __launch_bounds__(512) void k_post(const float* __restrict__ part,
                                              const float* __restrict__ fc1b,
                                              const float* __restrict__ fbw,
                                              const float* __restrict__ fbb,
                                              const float* __restrict__ fc2w,
                                              const float* __restrict__ fc2b,
                                              float* __restrict__ out,
                                              float* __restrict__ fc2o)
{
    const int t = threadIdx.x;
    const int im8 = t >> 6;                     // 0..7 == wave id
    const int tl = t & 63;                      // oc
    const int img = blockIdx.x * 8 + im8;
    float s = fc1b[tl];
    #pragma unroll
    for (int ks = 0; ks < 16; ++ks) s += part[((size_t)ks * NIMG + img) * 64 + tl];
    const float f = fmaxf(s, 0.f);
    __shared__ float flc[8][64];
    flc[im8][tl] = f;
    const float bs = wave_sum(f * fbw[tl]);
    if (tl == 0) out[800 + img] = 1.f / (1.f + expf(-(bs + fbb[0])));
    __syncthreads();
    #pragma unroll
    for (int q = 0; q < 2; ++q) {
        const int j = tl + q * 64;
        float a2 = fc2b[j];
        #pragma unroll 8
        for (int k = 0; k < 64; ++k) a2 = fmaf(flc[im8][k], fc2w[j * 64 + k], a2);
        fc2o[(size_t)img * 128 + j] = a2;
    }
}

// ---------------- fusion + softmax + 32-iter water-filling rebalance --------
__global__ __launch_bounds__(64) void k_final(const float* __restrict__ hlast,
                                              const float* __restrict__ fc2o,
                                              const float* __restrict__ gw,
                                              const float* __restrict__ gb,
                                              const float* __restrict__ fw,
                                              const float* __restrict__ fb,
                                              const float* __restrict__ finw,
                                              const float* __restrict__ finb,
                                              float* __restrict__ out)
{
    const int b = blockIdx.x, t = threadIdx.x;
    __shared__ float cf[128], nf[64], fu[64];
    #pragma unroll
    for (int jj = 0; jj < 2; ++jj) {
        const int j = t + jj * 64;
        float s = 0.f;
        for (int n = 0; n < NSTK; ++n) s += fc2o[(size_t)(b * NSTK + n) * 128 + j];
        cf[j] = s * (1.0f / 50.0f);
    }
    float s = 0.f;
    if (t < NSTK) {
        s = gb[t];
        for (int k = 0; k < HID; ++k) s = fmaf(hlast[b * HID + k], gw[t * HID + k], s);
    }
    nf[t] = (t < NSTK) ? s : 0.f;
    __syncthreads();
    float f = fb[t];
    for (int k = 0; k < NSTK; ++k) f = fmaf(nf[k], fw[t * 178 + k], f);
    for (int k = 0; k < 128; ++k) f = fmaf(cf[k], fw[t * 178 + 50 + k], f);
    fu[t] = fmaxf(f, 0.f);
    __syncthreads();
    float L = -3.4e38f;
    if (t < NSTK) {
        L = finb[t];
        for (int k = 0; k < 64; ++k) L = fmaf(fu[k], finw[t * 64 + k], L);
    }
    const float m = wave_max(L);
    const float e = (t < NSTK) ? expf(L - m) : 0.f;
    const float se = wave_sum(e);
    const float wv = e / se;
    float old = wv;
    float wc = fminf(fmaxf(wv, 0.f), 0.1f);
    for (int it = 0; it < 32; ++it) {
        const float leftover = wave_sum(old - wc);
        const bool mask = (wc != 0.1f);
        const float ssum = wave_sum(mask ? wc : 0.f);
        const float gift = (mask && ssum > 0.f) ? leftover * wc / ssum : 0.f;
        old = wc + gift;
        wc = fminf(fmaxf(old, 0.f), 0.1f);
    }
    if (t < NSTK) out[b * NSTK + t] = wc;
}

// ---------------------------------------------------------------------------
extern "C" void kernel_launch(void* const* d_in, const int* in_sizes, int n_in,
                              void* d_out, int out_size, void* d_ws, size_t ws_size,
                              hipStream_t stream)
{
    const float* x_num = (const float*)d_in[0];
    const float* x_img = (const float*)d_in[1];
    const float* c1w  = (const float*)d_in[2];
    const float* c1b  = (const float*)d_in[3];
    const float* c2w  = (const float*)d_in[4];
    const float* c2b  = (const float*)d_in[5];
    const float* fc1w = (const float*)d_in[6];
    const float* fc1b = (const float*)d_in[7];
    const float* fbw  = (const float*)d_in[8];
    const float* fbb  = (const float*)d_in[9];
    const float* fc2w = (const float*)d_in[10];
    const float* fc2b = (const float*)d_in[11];
    const float* wih  = (const float*)d_in[12];
    const float* whh  = (const float*)d_in[13];
    const float* bih  = (const float*)d_in[14];
    const float* bhh  = (const float*)d_in[15];
    const float* gw   = (const float*)d_in[16];
    const float* gb   = (const float*)d_in[17];
    const float* fw   = (const float*)d_in[18];
    const float* fb   = (const float*)d_in[19];
    const float* finw = (const float*)d_in[20];
    const float* finb = (const float*)d_in[21];
    float* out = (float*)d_out;
    float* ws  = (float*)d_ws;
    if (ws_size < (size_t)WS_FLOATS * 4) return;

    ushort_t* whhf  = (ushort_t*)(ws + OFF_WHHF);
    ushort_t* wprep = (ushort_t*)(ws + OFF_WPREP);
    ushort_t* wfc1  = (ushort_t*)(ws + OFF_WFC1);
    float* GI       = ws + OFF_GI;
    float* hlast    = ws + OFF_HLAST;
    ushort_t* pool2 = (ushort_t*)(ws + OFF_POOL2);
    float* fc2o     = ws + OFF_FC2O;
    float* part     = ws + OFF_PART;
    unsigned int* w1h = (unsigned int*)(ws + OFF_W1H);

    (void)hipFuncSetAttribute(reinterpret_cast<const void*>(k_mega),
                              hipFuncAttributeMaxDynamicSharedMemorySize, SMEM_BYTES);

    k_pre   <<<960 + 2737, 384, 0, stream>>>(x_num, wih, bih, whh, c2w, fc1w, c1w, c1b,
                                             GI, whhf, wprep, wfc1, w1h);
    k_mega  <<<2 * NIMG + 1, 512, SMEM_BYTES, stream>>>(x_img, w1h, c2b, wprep,
                                                        GI, whhf, bhh, pool2, hlast);
    k_fc1   <<<50 * 16, 256, 0, stream>>>(pool2, wfc1, part);
    k_post  <<<100, 512, 0, stream>>>(part, fc1b, fbw, fbb, fc2w, fc2b, out, fc2o);
    k_final <<<NBATCH, 64, 0, stream>>>(hlast, fc2o, gw, gb, fw, fb, finw, finb, out);
}